// Round 3
// baseline (1015.016 us; speedup 1.0000x reference)
//
#include <hip/hip_runtime.h>
#include <hip/hip_bf16.h>

typedef __hip_bfloat16 hb;
typedef __bf16 bf16x8 __attribute__((ext_vector_type(8)));
typedef float f32x4 __attribute__((ext_vector_type(4)));

#define SEQ 4096
#define EMBED 1024
#define NHEAD 4
#define HDIM 256
#define FFD 4096
#define NEXP 8
#define ADIM 496

static __device__ __forceinline__ float b2f(hb x) { return __bfloat162float(x); }
static __device__ __forceinline__ hb f2b(float x) { return __float2bfloat16(x); }
static __device__ __forceinline__ hb cvt_hb(float x) { return __float2bfloat16(x); }
static __device__ __forceinline__ hb cvt_hb(hb x) { return x; }

#define GLOAD_LDS16(g, l)                                                      \
  __builtin_amdgcn_global_load_lds(                                            \
      (const __attribute__((address_space(1))) void*)(g),                      \
      (__attribute__((address_space(3))) void*)(l), 16, 0, 0)

// ---------------------------------------------------------------------------
// Generic batched GEMM: C[M,N] = A[M,K] @ Bt[N,K]^T (+bias[col]) (+relu)
// 128x128 tile, BK=32, 4 waves (2x2 of 64x64), mfma_f32_16x16x32_bf16.
// M, N multiples of 128; K multiple of 32. bf16 in/out, fp32 accumulate.
// bias is fp32 (raw input pointers).
// ---------------------------------------------------------------------------
__global__ __launch_bounds__(256) void gemm_bt(
    const hb* __restrict__ A, long lda, long bA,
    const hb* __restrict__ B, long ldb, long bB,
    hb* __restrict__ C, long ldc, long bC,
    int K, const float* __restrict__ bias, int relu) {
  __shared__ __align__(16) hb sA[128 * 32];
  __shared__ __align__(16) hb sB[128 * 32];
  const int z = blockIdx.z;
  A += (long)z * bA;
  B += (long)z * bB;
  C += (long)z * bC;
  const int m0 = blockIdx.y * 128, n0 = blockIdx.x * 128;
  const int tid = threadIdx.x;
  const int wave = tid >> 6, lane = tid & 63;
  const int quad = lane >> 4, lm = lane & 15;
  const int wr = wave >> 1, wc = wave & 1;

  // staging: chunk c (8 bf16 = 16B) covers row c>>2, cols (c&3)*8..+8 of tile.
  // HW puts lane's 16B at (wave-uniform lds base) + lane*16.
  const int r0 = tid >> 2, cg = (tid & 3) * 8;
  const hb* Ag0 = A + (long)(m0 + r0) * lda + cg;
  const hb* Ag1 = A + (long)(m0 + r0 + 64) * lda + cg;
  const hb* Bg0 = B + (long)(n0 + r0) * ldb + cg;
  const hb* Bg1 = B + (long)(n0 + r0 + 64) * ldb + cg;
  hb* sA0 = sA + wave * 512;
  hb* sA1 = sA + 2048 + wave * 512;
  hb* sB0 = sB + wave * 512;
  hb* sB1 = sB + 2048 + wave * 512;

  f32x4 acc[4][4] = {};

  for (int kt = 0; kt < K; kt += 32) {
    GLOAD_LDS16(Ag0 + kt, sA0);
    GLOAD_LDS16(Ag1 + kt, sA1);
    GLOAD_LDS16(Bg0 + kt, sB0);
    GLOAD_LDS16(Bg1 + kt, sB1);
    __syncthreads();
    bf16x8 av[4], bv[4];
#pragma unroll
    for (int i = 0; i < 4; i++)
      av[i] = *(const bf16x8*)&sA[(wr * 64 + i * 16 + lm) * 32 + quad * 8];
#pragma unroll
    for (int i = 0; i < 4; i++)
      bv[i] = *(const bf16x8*)&sB[(wc * 64 + i * 16 + lm) * 32 + quad * 8];
#pragma unroll
    for (int i = 0; i < 4; i++)
#pragma unroll
      for (int j = 0; j < 4; j++)
        acc[i][j] =
            __builtin_amdgcn_mfma_f32_16x16x32_bf16(av[i], bv[j], acc[i][j], 0, 0, 0);
    __syncthreads();
  }

#pragma unroll
  for (int j = 0; j < 4; j++) {
    const int col = n0 + wc * 64 + j * 16 + lm;
    const float bval = bias ? bias[col] : 0.f;
#pragma unroll
    for (int i = 0; i < 4; i++) {
      const int row = m0 + wr * 64 + i * 16 + quad * 4;
#pragma unroll
      for (int rr = 0; rr < 4; rr++) {
        float v = acc[i][j][rr] + bval;
        if (relu) v = fmaxf(v, 0.f);
        C[(long)(row + rr) * ldc + col] = f2b(v);
      }
    }
  }
}

// ---------------------------------------------------------------------------
// Batched transpose to bf16: out[c][r] = cvt(in[r][c]); zero-pads [Cin,Cout).
// ---------------------------------------------------------------------------
template <typename Tin>
__global__ __launch_bounds__(256) void transpose_to_bf16(
    const Tin* __restrict__ in, hb* __restrict__ out, int R, int Cin, int Cout,
    int ldin, int ldout, long inBatch, long outBatch) {
  __shared__ hb tile[32][33];
  const int z = blockIdx.z;
  in += (long)z * inBatch;
  out += (long)z * outBatch;
  const int c0 = blockIdx.x * 32, r0 = blockIdx.y * 32;
  const int tx = threadIdx.x, ty = threadIdx.y;  // 32 x 8
#pragma unroll
  for (int i = 0; i < 32; i += 8) {
    const int r = r0 + ty + i, c = c0 + tx;
    hb v = f2b(0.f);
    if (r < R && c < Cin) v = cvt_hb(in[(long)r * ldin + c]);
    tile[ty + i][tx] = v;
  }
  __syncthreads();
#pragma unroll
  for (int i = 0; i < 32; i += 8) {
    const int c = c0 + ty + i, r = r0 + tx;
    if (c < Cout && r < R) out[(long)c * ldout + r] = tile[tx][ty + i];
  }
}

// ---------------------------------------------------------------------------
// h = concat(x, time_table[time], state)   fp32 inputs -> bf16 [SEQ, EMBED]
// ---------------------------------------------------------------------------
__global__ __launch_bounds__(256) void build_h_kernel(
    const float* __restrict__ x, const int* __restrict__ timev,
    const float* __restrict__ state, const float* __restrict__ ttab,
    hb* __restrict__ h) {
  const int s = blockIdx.x;
  for (int c = threadIdx.x; c < EMBED; c += 256) {
    float v;
    if (c < ADIM)
      v = x[(long)s * ADIM + c];
    else if (c < ADIM + 16)
      v = ttab[timev[s] * 16 + (c - ADIM)];
    else
      v = state[(long)s * 512 + (c - 512)];
    h[(long)s * EMBED + c] = f2b(v);
  }
}

// ---------------------------------------------------------------------------
// gate = softmax(h_fp32 @ gate_w + gate_b); top-2 -> comb[s, 8] (dense, fp32)
// FP32 h gathered straight from the raw inputs: top-k selection is
// discontinuous, so it must match the fp32 reference (bf16 h flips ~2.5% of
// rows' second expert -> O(1) per-row error).
// ---------------------------------------------------------------------------
__global__ __launch_bounds__(64) void gate_topk_kernel(
    const float* __restrict__ x, const int* __restrict__ timev,
    const float* __restrict__ state, const float* __restrict__ ttab,
    const float* __restrict__ gw, const float* __restrict__ gb,
    float* __restrict__ comb) {
  const int s = blockIdx.x;
  const int l = threadIdx.x;
  const int t = timev[s];
  float acc[8] = {0, 0, 0, 0, 0, 0, 0, 0};
  for (int e = l; e < EMBED; e += 64) {
    float hv;
    if (e < ADIM)
      hv = x[(long)s * ADIM + e];
    else if (e < ADIM + 16)
      hv = ttab[t * 16 + (e - ADIM)];
    else
      hv = state[(long)s * 512 + (e - 512)];
    const float* g = gw + e * 8;
#pragma unroll
    for (int n = 0; n < 8; n++) acc[n] += hv * g[n];
  }
#pragma unroll
  for (int o = 32; o; o >>= 1)
#pragma unroll
    for (int n = 0; n < 8; n++) acc[n] += __shfl_down(acc[n], o);
  if (l == 0) {
    float lg[8], m = -1e30f;
    for (int n = 0; n < 8; n++) {
      lg[n] = acc[n] + gb[n];
      m = fmaxf(m, lg[n]);
    }
    float den = 0.f;
    for (int n = 0; n < 8; n++) {
      lg[n] = expf(lg[n] - m);
      den += lg[n];
    }
    for (int n = 0; n < 8; n++) lg[n] /= den;
    int i1 = 0;
    for (int n = 1; n < 8; n++)
      if (lg[n] > lg[i1]) i1 = n;
    int i2 = (i1 == 0) ? 1 : 0;
    for (int n = 0; n < 8; n++) {
      if (n == i1) continue;
      if (lg[n] > lg[i2]) i2 = n;
    }
    float* c = comb + s * 8;
    for (int n = 0; n < 8; n++) c[n] = 0.f;
    c[i1] = lg[i1];
    c[i2] = lg[i2];
  }
}

// ---------------------------------------------------------------------------
// A'[s, n*1024+e] = comb[s,n] * h[s,e]   [SEQ, 8192] bf16
// ---------------------------------------------------------------------------
__global__ __launch_bounds__(256) void build_aprime_kernel(
    const hb* __restrict__ h, const float* __restrict__ comb,
    hb* __restrict__ ap) {
  const long i = (long)blockIdx.x * 256 + threadIdx.x;
  const long s = i >> 13;
  const int k = (int)(i & 8191);
  ap[i] = f2b(comb[s * 8 + (k >> 10)] * b2f(h[s * EMBED + (k & 1023)]));
}

// moe[s,f] += sum_n comb[s,n] * expert_b[n,f]   (expert_b fp32)
__global__ __launch_bounds__(256) void moe_bias_kernel(
    hb* __restrict__ moe, const float* __restrict__ comb,
    const float* __restrict__ eb) {
  const long i = (long)blockIdx.x * 256 + threadIdx.x;
  const long s = i >> 10;
  const int f = (int)(i & 1023);
  float v = b2f(moe[i]);
  const float* c = comb + s * 8;
#pragma unroll
  for (int n = 0; n < 8; n++) v += c[n] * eb[n * EMBED + f];
  moe[i] = f2b(v);
}

// ---------------------------------------------------------------------------
// row softmax over ncol with logit scale (in-place, bf16)
// ---------------------------------------------------------------------------
__global__ __launch_bounds__(256) void softmax_rows_kernel(hb* __restrict__ S,
                                                           int ncol,
                                                           float scale) {
  const long row = blockIdx.x;
  hb* p = S + row * (long)ncol;
  const int tid = threadIdx.x, wv = tid >> 6, ln = tid & 63;
  __shared__ float red[4];
  float m = -1e30f;
  for (int c = tid; c < ncol; c += 256) m = fmaxf(m, b2f(p[c]));
#pragma unroll
  for (int o = 32; o; o >>= 1) m = fmaxf(m, __shfl_down(m, o));
  if (ln == 0) red[wv] = m;
  __syncthreads();
  const float M = fmaxf(fmaxf(red[0], red[1]), fmaxf(red[2], red[3])) * scale;
  __syncthreads();
  float sum = 0.f;
  for (int c = tid; c < ncol; c += 256) sum += __expf(b2f(p[c]) * scale - M);
#pragma unroll
  for (int o = 32; o; o >>= 1) sum += __shfl_down(sum, o);
  if (ln == 0) red[wv] = sum;
  __syncthreads();
  const float inv = 1.f / (red[0] + red[1] + red[2] + red[3]);
  for (int c = tid; c < ncol; c += 256)
    p[c] = f2b(__expf(b2f(p[c]) * scale - M) * inv);
}

// ---------------------------------------------------------------------------
// LayerNorm over ncol: t = in + resid? + bias?; out = (t-mean)*rsqrt(var)*g+b
// in/resid bf16; bias/g/beta fp32; out -> bf16 (outb) or fp32 (outf).
// ---------------------------------------------------------------------------
__global__ __launch_bounds__(256) void ln_kernel(
    const hb* __restrict__ in, long ldin, const hb* __restrict__ resid,
    long ldr, const float* __restrict__ bias, const float* __restrict__ g,
    const float* __restrict__ beta, hb* __restrict__ outb,
    float* __restrict__ outf, long ldout, int ncol) {
  const int s = blockIdx.x, tid = threadIdx.x, wv = tid >> 6, ln = tid & 63;
  __shared__ float buf[1024];
  __shared__ float red[4];
  float sum = 0.f, sq = 0.f;
  for (int c = tid; c < ncol; c += 256) {
    float v = b2f(in[(long)s * ldin + c]);
    if (resid) v += b2f(resid[(long)s * ldr + c]);
    if (bias) v += bias[c];
    buf[c] = v;
    sum += v;
    sq += v * v;
  }
#pragma unroll
  for (int o = 32; o; o >>= 1) sum += __shfl_down(sum, o);
  if (ln == 0) red[wv] = sum;
  __syncthreads();
  const float S = red[0] + red[1] + red[2] + red[3];
  __syncthreads();
#pragma unroll
  for (int o = 32; o; o >>= 1) sq += __shfl_down(sq, o);
  if (ln == 0) red[wv] = sq;
  __syncthreads();
  const float Q = red[0] + red[1] + red[2] + red[3];
  const float mean = S / ncol;
  const float var = Q / ncol - mean * mean;
  const float r = rsqrtf(var + 1e-5f);
  for (int c = tid; c < ncol; c += 256) {
    const float o = (buf[c] - mean) * r * g[c] + beta[c];
    if (outf)
      outf[(long)s * ldout + c] = o;
    else
      outb[(long)s * ldout + c] = f2b(o);
  }
}

// ---------------------------------------------------------------------------
extern "C" void kernel_launch(void* const* d_in, const int* in_sizes, int n_in,
                              void* d_out, int out_size, void* d_ws,
                              size_t ws_size, hipStream_t stream) {
  const float* x = (const float*)d_in[0];
  const int* timev = (const int*)d_in[1];
  const float* state = (const float*)d_in[2];
  const float* ttab = (const float*)d_in[3];
  const float* expert_w = (const float*)d_in[4];
  const float* expert_b = (const float*)d_in[5];
  const float* gate_w = (const float*)d_in[6];
  const float* gate_b = (const float*)d_in[7];
  const float* in_proj_w = (const float*)d_in[8];
  const float* in_proj_b = (const float*)d_in[9];
  const float* out_proj_w = (const float*)d_in[10];
  const float* out_proj_b = (const float*)d_in[11];
  const float* ln1_g = (const float*)d_in[12];
  const float* ln1_b = (const float*)d_in[13];
  const float* ff1_w = (const float*)d_in[14];
  const float* ff1_b = (const float*)d_in[15];
  const float* ff2_w = (const float*)d_in[16];
  const float* ff2_b = (const float*)d_in[17];
  const float* ln2_g = (const float*)d_in[18];
  const float* ln2_b = (const float*)d_in[19];
  float* out = (float*)d_out;

  char* w = (char*)d_ws;
  // arena (bytes); later-stage buffers reuse dead regions
  hb* expertT = (hb*)(w + 0);            // [1024, 8192]  16 MB
  hb* inprojT = (hb*)(w + 16777216);     // [3072, 1024]   6 MB
  hb* outprojT = (hb*)(w + 23068672);    // [1024, 1024]   2 MB
  hb* ff1T = (hb*)(w + 25165824);        // [4096, 1024]   8 MB
  hb* ff2T = (hb*)(w + 33554432);        // [512, 4096]    4 MB (padded)
  float* comb = (float*)(w + 37748736);  // [4096, 8]    128 KB
  hb* moe = (hb*)(w + 37879808);         // [4096, 1024]   8 MB
  hb* h = (hb*)(w + 46268416);           // [4096, 1024]   8 MB (dead after A')
  hb* aprime = (hb*)(w + 54657024);      // [4096, 8192]  64 MB (dead after moe)
  hb* scores = (hb*)(w + 46268416);      // [2, 4096, 4096] 64 MB (reuses h+A')
  hb* out1 = (hb*)(w + 46268416);        // [4096, 1024]  (after attention)
  hb* ffmid = (hb*)(w + 54657024);       // [4096, 4096]  32 MB (reuse)
  hb* ff2out = (hb*)(w + 88211456);      // [4096, 512]    4 MB (reuse)
  hb* qkv = (hb*)(w + 121765888);        // [4096, 3072]  24 MB
  hb* vt = (hb*)(w + 146931712);         // [2, 256, 4096] 4 MB
  hb* ao = (hb*)(w + 151126016);         // [4096, 1024]   8 MB
  hb* ao2 = (hb*)(w + 159514624);        // [4096, 1024]   8 MB
  (void)in_sizes; (void)n_in; (void)out_size; (void)ws_size;

  const dim3 tb(32, 8);
  // 1) transpose all weights to [out, in] (Bt layout), fp32 -> bf16
  transpose_to_bf16<float><<<dim3(32, 32, 8), tb, 0, stream>>>(
      expert_w, expertT, 1024, 1024, 1024, 1024, 8192, 1048576L, 1024L);
  transpose_to_bf16<float><<<dim3(96, 32, 1), tb, 0, stream>>>(
      in_proj_w, inprojT, 1024, 3072, 3072, 3072, 1024, 0, 0);
  transpose_to_bf16<float><<<dim3(32, 32, 1), tb, 0, stream>>>(
      out_proj_w, outprojT, 1024, 1024, 1024, 1024, 1024, 0, 0);
  transpose_to_bf16<float><<<dim3(128, 32, 1), tb, 0, stream>>>(
      ff1_w, ff1T, 1024, 4096, 4096, 4096, 1024, 0, 0);
  transpose_to_bf16<float><<<dim3(16, 128, 1), tb, 0, stream>>>(
      ff2_w, ff2T, 4096, ADIM, 512, ADIM, 4096, 0, 0);

  // 2) h (bf16 for GEMMs), gate/top-2 in fp32, A'
  build_h_kernel<<<dim3(SEQ), 256, 0, stream>>>(x, timev, state, ttab, h);
  gate_topk_kernel<<<dim3(SEQ), 64, 0, stream>>>(x, timev, state, ttab, gate_w,
                                                 gate_b, comb);
  build_aprime_kernel<<<dim3(SEQ * 8192 / 256), 256, 0, stream>>>(h, comb, aprime);

  // 3) MoE: moe = A' @ expertT^T  (+ comb-weighted expert bias)
  gemm_bt<<<dim3(8, 32, 1), 256, 0, stream>>>(aprime, 8192, 0, expertT, 8192, 0,
                                              moe, 1024, 0, 8192, nullptr, 0);
  moe_bias_kernel<<<dim3(SEQ * 1024 / 256), 256, 0, stream>>>(moe, comb, expert_b);

  // 4) qkv = moe @ in_proj + b
  gemm_bt<<<dim3(24, 32, 1), 256, 0, stream>>>(moe, 1024, 0, inprojT, 1024, 0,
                                               qkv, 3072, 0, 1024, in_proj_b, 0);

  // 5) attention, two heads per pass (scores arena = 64 MB)
  for (int hp = 0; hp < 2; ++hp) {
    const hb* qb = qkv + hp * 512;
    const hb* kb = qkv + 1024 + hp * 512;
    const hb* vb = qkv + 2048 + hp * 512;
    gemm_bt<<<dim3(32, 32, 2), 256, 0, stream>>>(
        qb, 3072, 256, kb, 3072, 256, scores, 4096, (long)SEQ * SEQ, HDIM,
        nullptr, 0);
    softmax_rows_kernel<<<dim3(2 * SEQ), 256, 0, stream>>>(scores, SEQ, 0.0625f);
    transpose_to_bf16<hb><<<dim3(8, 128, 2), tb, 0, stream>>>(
        vb, vt, SEQ, HDIM, HDIM, 3072, 4096, 256L, 1048576L);
    gemm_bt<<<dim3(2, 32, 2), 256, 0, stream>>>(
        scores, 4096, (long)SEQ * SEQ, vt, 4096, 1048576L, ao + hp * 512, 1024,
        256, SEQ, nullptr, 0);
  }

  // 6) out_proj, residual LN
  gemm_bt<<<dim3(8, 32, 1), 256, 0, stream>>>(ao, 1024, 0, outprojT, 1024, 0,
                                              ao2, 1024, 0, 1024, out_proj_b, 0);
  ln_kernel<<<dim3(SEQ), 256, 0, stream>>>(moe, 1024, ao2, 1024, nullptr, ln1_g,
                                           ln1_b, out1, nullptr, 1024, 1024);

  // 7) FFN
  gemm_bt<<<dim3(32, 32, 1), 256, 0, stream>>>(out1, 1024, 0, ff1T, 1024, 0,
                                               ffmid, 4096, 0, 1024, ff1_b, 1);
  gemm_bt<<<dim3(4, 32, 1), 256, 0, stream>>>(ffmid, 4096, 0, ff2T, 4096, 0,
                                              ff2out, 512, 0, 4096, nullptr, 0);

  // 8) final LN over 496 cols -> d_out (fp32)
  ln_kernel<<<dim3(SEQ), 256, 0, stream>>>(ff2out, 512, nullptr, 0, ff2_b,
                                           ln2_g, ln2_b, nullptr, out, ADIM,
                                           ADIM);
}

// Round 4
// 842.383 us; speedup vs baseline: 1.2049x; 1.2049x over previous
//
#include <hip/hip_runtime.h>
#include <hip/hip_bf16.h>

typedef __hip_bfloat16 hb;
typedef __bf16 bf16x8 __attribute__((ext_vector_type(8)));
typedef float f32x4 __attribute__((ext_vector_type(4)));

#define SEQ 4096
#define EMBED 1024
#define NHEAD 4
#define HDIM 256
#define FFD 4096
#define NEXP 8
#define ADIM 496
#define NSLOT 9216  // 8192 assignments + 8 experts x 127 max padding, 128-aligned

static __device__ __forceinline__ float b2f(hb x) { return __bfloat162float(x); }
static __device__ __forceinline__ hb f2b(float x) { return __float2bfloat16(x); }
static __device__ __forceinline__ hb cvt_hb(float x) { return __float2bfloat16(x); }
static __device__ __forceinline__ hb cvt_hb(hb x) { return x; }

#define GLOAD_LDS16(g, l)                                                      \
  __builtin_amdgcn_global_load_lds(                                            \
      (const __attribute__((address_space(1))) void*)(g),                      \
      (__attribute__((address_space(3))) void*)(l), 16, 0, 0)

// ---------------------------------------------------------------------------
// Generic batched GEMM: C[M,N] = A[M,K] @ Bt[N,K]^T (+bias[col]) (+relu)
// 128x128 tile, BK=32, 4 waves (2x2 of 64x64), mfma_f32_16x16x32_bf16.
// LDS k-group XOR swizzle: chunk (row, j) holds kgrp j^(row&3) -> fragment
// read bank conflict drops 8-way -> 2-way (free, m136).
// ---------------------------------------------------------------------------
__global__ __launch_bounds__(256) void gemm_bt(
    const hb* __restrict__ A, long lda, long bA,
    const hb* __restrict__ B, long ldb, long bB,
    hb* __restrict__ C, long ldc, long bC,
    int K, const float* __restrict__ bias, int relu) {
  __shared__ __align__(16) hb sA[128 * 32];
  __shared__ __align__(16) hb sB[128 * 32];
  const int z = blockIdx.z;
  A += (long)z * bA;
  B += (long)z * bB;
  C += (long)z * bC;
  const int m0 = blockIdx.y * 128, n0 = blockIdx.x * 128;
  const int tid = threadIdx.x;
  const int wave = tid >> 6, lane = tid & 63;
  const int quad = lane >> 4, lm = lane & 15;
  const int wr = wave >> 1, wc = wave & 1;

  const int r0 = tid >> 2;
  const int cg = 8 * ((tid & 3) ^ ((tid >> 2) & 3));  // XOR-swizzled k-group
  const hb* Ag0 = A + (long)(m0 + r0) * lda + cg;
  const hb* Ag1 = A + (long)(m0 + r0 + 64) * lda + cg;
  const hb* Bg0 = B + (long)(n0 + r0) * ldb + cg;
  const hb* Bg1 = B + (long)(n0 + r0 + 64) * ldb + cg;
  hb* sA0 = sA + wave * 512;
  hb* sA1 = sA + 2048 + wave * 512;
  hb* sB0 = sB + wave * 512;
  hb* sB1 = sB + 2048 + wave * 512;

  f32x4 acc[4][4] = {};

  for (int kt = 0; kt < K; kt += 32) {
    GLOAD_LDS16(Ag0 + kt, sA0);
    GLOAD_LDS16(Ag1 + kt, sA1);
    GLOAD_LDS16(Bg0 + kt, sB0);
    GLOAD_LDS16(Bg1 + kt, sB1);
    __syncthreads();
    bf16x8 av[4], bv[4];
#pragma unroll
    for (int i = 0; i < 4; i++) {
      const int row = wr * 64 + i * 16 + lm;
      av[i] = *(const bf16x8*)&sA[row * 32 + (quad ^ (lm & 3)) * 8];
    }
#pragma unroll
    for (int i = 0; i < 4; i++) {
      const int row = wc * 64 + i * 16 + lm;
      bv[i] = *(const bf16x8*)&sB[row * 32 + (quad ^ (lm & 3)) * 8];
    }
#pragma unroll
    for (int i = 0; i < 4; i++)
#pragma unroll
      for (int j = 0; j < 4; j++)
        acc[i][j] =
            __builtin_amdgcn_mfma_f32_16x16x32_bf16(av[i], bv[j], acc[i][j], 0, 0, 0);
    __syncthreads();
  }

#pragma unroll
  for (int j = 0; j < 4; j++) {
    const int col = n0 + wc * 64 + j * 16 + lm;
    const float bval = bias ? bias[col] : 0.f;
#pragma unroll
    for (int i = 0; i < 4; i++) {
      const int row = m0 + wr * 64 + i * 16 + quad * 4;
#pragma unroll
      for (int rr = 0; rr < 4; rr++) {
        float v = acc[i][j][rr] + bval;
        if (relu) v = fmaxf(v, 0.f);
        C[(long)(row + rr) * ldc + col] = f2b(v);
      }
    }
  }
}

// ---------------------------------------------------------------------------
// MoE gather-GEMM: slotout[slot, :] = h[slot_token[slot], :] @ expertT[e]^T
// Fixed grid (8, 72); row-blocks beyond the used segments early-exit on
// eblk=-1 (data-dependent branch, same launch shape every call).
// ---------------------------------------------------------------------------
__global__ __launch_bounds__(256) void gemm_moe(
    const hb* __restrict__ h, const hb* __restrict__ expertT,
    const int* __restrict__ slot_token, const int* __restrict__ eblk,
    hb* __restrict__ slotout) {
  const int e = eblk[blockIdx.y];
  if (e < 0) return;
  __shared__ __align__(16) hb sA[128 * 32];
  __shared__ __align__(16) hb sB[128 * 32];
  const int m0 = blockIdx.y * 128, n0 = blockIdx.x * 128;
  const int tid = threadIdx.x;
  const int wave = tid >> 6, lane = tid & 63;
  const int quad = lane >> 4, lm = lane & 15;
  const int wr = wave >> 1, wc = wave & 1;

  const int r0 = tid >> 2;
  const int cg = 8 * ((tid & 3) ^ ((tid >> 2) & 3));
  const int t0 = slot_token[m0 + r0];
  const int t1 = slot_token[m0 + r0 + 64];
  const hb* B = expertT + ((long)e << 20);
  const hb* Ag0 = h + (long)t0 * EMBED + cg;
  const hb* Ag1 = h + (long)t1 * EMBED + cg;
  const hb* Bg0 = B + (long)(n0 + r0) * EMBED + cg;
  const hb* Bg1 = B + (long)(n0 + r0 + 64) * EMBED + cg;
  hb* sA0 = sA + wave * 512;
  hb* sA1 = sA + 2048 + wave * 512;
  hb* sB0 = sB + wave * 512;
  hb* sB1 = sB + 2048 + wave * 512;

  f32x4 acc[4][4] = {};

  for (int kt = 0; kt < EMBED; kt += 32) {
    GLOAD_LDS16(Ag0 + kt, sA0);
    GLOAD_LDS16(Ag1 + kt, sA1);
    GLOAD_LDS16(Bg0 + kt, sB0);
    GLOAD_LDS16(Bg1 + kt, sB1);
    __syncthreads();
    bf16x8 av[4], bv[4];
#pragma unroll
    for (int i = 0; i < 4; i++) {
      const int row = wr * 64 + i * 16 + lm;
      av[i] = *(const bf16x8*)&sA[row * 32 + (quad ^ (lm & 3)) * 8];
    }
#pragma unroll
    for (int i = 0; i < 4; i++) {
      const int row = wc * 64 + i * 16 + lm;
      bv[i] = *(const bf16x8*)&sB[row * 32 + (quad ^ (lm & 3)) * 8];
    }
#pragma unroll
    for (int i = 0; i < 4; i++)
#pragma unroll
      for (int j = 0; j < 4; j++)
        acc[i][j] =
            __builtin_amdgcn_mfma_f32_16x16x32_bf16(av[i], bv[j], acc[i][j], 0, 0, 0);
    __syncthreads();
  }

#pragma unroll
  for (int j = 0; j < 4; j++) {
    const int col = n0 + wc * 64 + j * 16 + lm;
#pragma unroll
    for (int i = 0; i < 4; i++) {
      const int row = m0 + wr * 64 + i * 16 + quad * 4;
#pragma unroll
      for (int rr = 0; rr < 4; rr++)
        slotout[(long)(row + rr) * EMBED + col] = f2b(acc[i][j][rr]);
    }
  }
}

// ---------------------------------------------------------------------------
// Batched transpose to bf16: out[c][r] = cvt(in[r][c]); zero-pads [Cin,Cout).
// ---------------------------------------------------------------------------
template <typename Tin>
__global__ __launch_bounds__(256) void transpose_to_bf16(
    const Tin* __restrict__ in, hb* __restrict__ out, int R, int Cin, int Cout,
    int ldin, int ldout, long inBatch, long outBatch) {
  __shared__ hb tile[32][33];
  const int z = blockIdx.z;
  in += (long)z * inBatch;
  out += (long)z * outBatch;
  const int c0 = blockIdx.x * 32, r0 = blockIdx.y * 32;
  const int tx = threadIdx.x, ty = threadIdx.y;  // 32 x 8
#pragma unroll
  for (int i = 0; i < 32; i += 8) {
    const int r = r0 + ty + i, c = c0 + tx;
    hb v = f2b(0.f);
    if (r < R && c < Cin) v = cvt_hb(in[(long)r * ldin + c]);
    tile[ty + i][tx] = v;
  }
  __syncthreads();
#pragma unroll
  for (int i = 0; i < 32; i += 8) {
    const int c = c0 + ty + i, r = r0 + tx;
    if (c < Cout && r < R) out[(long)c * ldout + r] = tile[tx][ty + i];
  }
}

// ---------------------------------------------------------------------------
// h = concat(x, time_table[time], state)   fp32 inputs -> bf16 [SEQ, EMBED]
// ---------------------------------------------------------------------------
__global__ __launch_bounds__(256) void build_h_kernel(
    const float* __restrict__ x, const int* __restrict__ timev,
    const float* __restrict__ state, const float* __restrict__ ttab,
    hb* __restrict__ h) {
  const int s = blockIdx.x;
  for (int c = threadIdx.x; c < EMBED; c += 256) {
    float v;
    if (c < ADIM)
      v = x[(long)s * ADIM + c];
    else if (c < ADIM + 16)
      v = ttab[timev[s] * 16 + (c - ADIM)];
    else
      v = state[(long)s * 512 + (c - 512)];
    h[(long)s * EMBED + c] = f2b(v);
  }
}

// ---------------------------------------------------------------------------
// gate logits in fp32 straight from raw inputs (top-k is discontinuous; must
// match fp32 reference). Writes top-2 (expert, prob) per token.
// ---------------------------------------------------------------------------
__global__ __launch_bounds__(64) void gate_topk_kernel(
    const float* __restrict__ x, const int* __restrict__ timev,
    const float* __restrict__ state, const float* __restrict__ ttab,
    const float* __restrict__ gw, const float* __restrict__ gb,
    int* __restrict__ tok_e, float* __restrict__ tok_w) {
  const int s = blockIdx.x;
  const int l = threadIdx.x;
  const int t = timev[s];
  float acc[8] = {0, 0, 0, 0, 0, 0, 0, 0};
  for (int e = l; e < EMBED; e += 64) {
    float hv;
    if (e < ADIM)
      hv = x[(long)s * ADIM + e];
    else if (e < ADIM + 16)
      hv = ttab[t * 16 + (e - ADIM)];
    else
      hv = state[(long)s * 512 + (e - 512)];
    const float* g = gw + e * 8;
#pragma unroll
    for (int n = 0; n < 8; n++) acc[n] += hv * g[n];
  }
#pragma unroll
  for (int o = 32; o; o >>= 1)
#pragma unroll
    for (int n = 0; n < 8; n++) acc[n] += __shfl_down(acc[n], o);
  if (l == 0) {
    float lg[8], m = -1e30f;
    for (int n = 0; n < 8; n++) {
      lg[n] = acc[n] + gb[n];
      m = fmaxf(m, lg[n]);
    }
    float den = 0.f;
    for (int n = 0; n < 8; n++) {
      lg[n] = expf(lg[n] - m);
      den += lg[n];
    }
    for (int n = 0; n < 8; n++) lg[n] /= den;
    int i1 = 0;
    for (int n = 1; n < 8; n++)
      if (lg[n] > lg[i1]) i1 = n;
    int i2 = (i1 == 0) ? 1 : 0;
    for (int n = 0; n < 8; n++) {
      if (n == i1) continue;
      if (lg[n] > lg[i2]) i2 = n;
    }
    tok_e[2 * s] = i1;
    tok_w[2 * s] = lg[i1];
    tok_e[2 * s + 1] = i2;
    tok_w[2 * s + 1] = lg[i2];
  }
}

// ---------------------------------------------------------------------------
// Single-block grouping: histogram -> 128-aligned segment offsets ->
// slot assignment (order within a segment is irrelevant: per-token result is
// order-independent) + per-row-block expert id.
// ---------------------------------------------------------------------------
__global__ __launch_bounds__(256) void group_kernel(
    const int* __restrict__ tok_e, int* __restrict__ slot_token,
    int* __restrict__ token_slot, int* __restrict__ eblk) {
  __shared__ int cnt[8], off[9], cur[8];
  const int tid = threadIdx.x;
  if (tid < 8) cnt[tid] = 0;
  for (int i = tid; i < NSLOT; i += 256) slot_token[i] = 0;  // padding -> tok 0
  __syncthreads();
  for (int i = tid; i < 2 * SEQ; i += 256) atomicAdd(&cnt[tok_e[i]], 1);
  __syncthreads();
  if (tid == 0) {
    int o = 0;
    for (int n = 0; n < 8; n++) {
      off[n] = o;
      cur[n] = o;
      o += (cnt[n] + 127) & ~127;
    }
    off[8] = o;
  }
  __syncthreads();
  if (tid < NSLOT / 128) {
    const int rb = tid * 128;
    int e = -1;
    for (int n = 0; n < 8; n++)
      if (rb >= off[n] && rb < off[n + 1]) e = n;
    eblk[tid] = e;
  }
  for (int i = tid; i < 2 * SEQ; i += 256) {
    const int e = tok_e[i];
    const int slot = atomicAdd(&cur[e], 1);
    slot_token[slot] = i >> 1;
    token_slot[i] = slot;
  }
}

// moe[s,:] = sum_k w_k * (slotout[slot_k,:] + expert_b[e_k,:])
__global__ __launch_bounds__(256) void moe_combine_kernel(
    const hb* __restrict__ slotout, const int* __restrict__ token_slot,
    const float* __restrict__ tok_w, const int* __restrict__ tok_e,
    const float* __restrict__ eb, hb* __restrict__ moe) {
  const int s = blockIdx.x, tid = threadIdx.x;
  const int s0 = token_slot[2 * s], s1 = token_slot[2 * s + 1];
  const float w0 = tok_w[2 * s], w1 = tok_w[2 * s + 1];
  const int e0 = tok_e[2 * s], e1 = tok_e[2 * s + 1];
  const hb* r0 = slotout + (long)s0 * EMBED;
  const hb* r1 = slotout + (long)s1 * EMBED;
  const float* b0 = eb + e0 * EMBED;
  const float* b1 = eb + e1 * EMBED;
  for (int c = tid; c < EMBED; c += 256) {
    const float v = w0 * (b2f(r0[c]) + b0[c]) + w1 * (b2f(r1[c]) + b1[c]);
    moe[(long)s * EMBED + c] = f2b(v);
  }
}

// ---------------------------------------------------------------------------
// row softmax over ncol with logit scale (in-place, bf16)
// ---------------------------------------------------------------------------
__global__ __launch_bounds__(256) void softmax_rows_kernel(hb* __restrict__ S,
                                                           int ncol,
                                                           float scale) {
  const long row = blockIdx.x;
  hb* p = S + row * (long)ncol;
  const int tid = threadIdx.x, wv = tid >> 6, ln = tid & 63;
  __shared__ float red[4];
  float m = -1e30f;
  for (int c = tid; c < ncol; c += 256) m = fmaxf(m, b2f(p[c]));
#pragma unroll
  for (int o = 32; o; o >>= 1) m = fmaxf(m, __shfl_down(m, o));
  if (ln == 0) red[wv] = m;
  __syncthreads();
  const float M = fmaxf(fmaxf(red[0], red[1]), fmaxf(red[2], red[3])) * scale;
  __syncthreads();
  float sum = 0.f;
  for (int c = tid; c < ncol; c += 256) sum += __expf(b2f(p[c]) * scale - M);
#pragma unroll
  for (int o = 32; o; o >>= 1) sum += __shfl_down(sum, o);
  if (ln == 0) red[wv] = sum;
  __syncthreads();
  const float inv = 1.f / (red[0] + red[1] + red[2] + red[3]);
  for (int c = tid; c < ncol; c += 256)
    p[c] = f2b(__expf(b2f(p[c]) * scale - M) * inv);
}

// ---------------------------------------------------------------------------
// LayerNorm over ncol: t = in + resid? + bias?; out = (t-mean)*rsqrt(var)*g+b
// ---------------------------------------------------------------------------
__global__ __launch_bounds__(256) void ln_kernel(
    const hb* __restrict__ in, long ldin, const hb* __restrict__ resid,
    long ldr, const float* __restrict__ bias, const float* __restrict__ g,
    const float* __restrict__ beta, hb* __restrict__ outb,
    float* __restrict__ outf, long ldout, int ncol) {
  const int s = blockIdx.x, tid = threadIdx.x, wv = tid >> 6, ln = tid & 63;
  __shared__ float buf[1024];
  __shared__ float red[4];
  float sum = 0.f, sq = 0.f;
  for (int c = tid; c < ncol; c += 256) {
    float v = b2f(in[(long)s * ldin + c]);
    if (resid) v += b2f(resid[(long)s * ldr + c]);
    if (bias) v += bias[c];
    buf[c] = v;
    sum += v;
    sq += v * v;
  }
#pragma unroll
  for (int o = 32; o; o >>= 1) sum += __shfl_down(sum, o);
  if (ln == 0) red[wv] = sum;
  __syncthreads();
  const float S = red[0] + red[1] + red[2] + red[3];
  __syncthreads();
#pragma unroll
  for (int o = 32; o; o >>= 1) sq += __shfl_down(sq, o);
  if (ln == 0) red[wv] = sq;
  __syncthreads();
  const float Q = red[0] + red[1] + red[2] + red[3];
  const float mean = S / ncol;
  const float var = Q / ncol - mean * mean;
  const float r = rsqrtf(var + 1e-5f);
  for (int c = tid; c < ncol; c += 256) {
    const float o = (buf[c] - mean) * r * g[c] + beta[c];
    if (outf)
      outf[(long)s * ldout + c] = o;
    else
      outb[(long)s * ldout + c] = f2b(o);
  }
}

// ---------------------------------------------------------------------------
extern "C" void kernel_launch(void* const* d_in, const int* in_sizes, int n_in,
                              void* d_out, int out_size, void* d_ws,
                              size_t ws_size, hipStream_t stream) {
  const float* x = (const float*)d_in[0];
  const int* timev = (const int*)d_in[1];
  const float* state = (const float*)d_in[2];
  const float* ttab = (const float*)d_in[3];
  const float* expert_w = (const float*)d_in[4];
  const float* expert_b = (const float*)d_in[5];
  const float* gate_w = (const float*)d_in[6];
  const float* gate_b = (const float*)d_in[7];
  const float* in_proj_w = (const float*)d_in[8];
  const float* in_proj_b = (const float*)d_in[9];
  const float* out_proj_w = (const float*)d_in[10];
  const float* out_proj_b = (const float*)d_in[11];
  const float* ln1_g = (const float*)d_in[12];
  const float* ln1_b = (const float*)d_in[13];
  const float* ff1_w = (const float*)d_in[14];
  const float* ff1_b = (const float*)d_in[15];
  const float* ff2_w = (const float*)d_in[16];
  const float* ff2_b = (const float*)d_in[17];
  const float* ln2_g = (const float*)d_in[18];
  const float* ln2_b = (const float*)d_in[19];
  float* out = (float*)d_out;

  char* w = (char*)d_ws;
  // arena (bytes); later-stage buffers reuse dead regions
  hb* expertT = (hb*)(w + 0);             // [8][1024,1024] 16 MB
  hb* inprojT = (hb*)(w + 16777216);      // [3072, 1024]   6 MB
  hb* outprojT = (hb*)(w + 23068672);     // [1024, 1024]   2 MB
  hb* ff1T = (hb*)(w + 25165824);         // [4096, 1024]   8 MB
  hb* ff2T = (hb*)(w + 33554432);         // [512, 4096]    4 MB (padded)
  int* tok_e = (int*)(w + 37748736);      // [8192]        32 KB
  float* tok_w = (float*)(w + 37781504);  // [8192]        32 KB
  int* slot_token = (int*)(w + 37814272); // [9216]        36 KB
  int* token_slot = (int*)(w + 37851136); // [8192]        32 KB
  int* eblk = (int*)(w + 37883904);       // [72]
  hb* moe = (hb*)(w + 37910528);          // [4096, 1024]   8 MB
  hb* h = (hb*)(w + 46299136);            // [4096, 1024]   8 MB (dead after MoE)
  hb* slotout = (hb*)(w + 54689792);      // [9216, 1024]  18.9 MB (dead after combine)
  hb* scores = (hb*)(w + 54689792);       // [2, 4096, 4096] 64 MB (after MoE; reuse)
  hb* out1 = (hb*)(w + 46299136);         // [4096, 1024]  (reuses h after attention)
  hb* ffmid = (hb*)(w + 54689792);        // [4096, 4096]  32 MB (reuse scores)
  hb* ff2out = (hb*)(w + 88244224);       // [4096, 512]    4 MB
  hb* qkv = (hb*)(w + 121765888);         // [4096, 3072]  24 MB
  hb* vt = (hb*)(w + 146931712);          // [2, 256, 4096] 4 MB
  hb* ao = (hb*)(w + 151126016);          // [4096, 1024]   8 MB
  hb* ao2 = (hb*)(w + 159514624);         // [4096, 1024]   8 MB
  (void)in_sizes; (void)n_in; (void)out_size; (void)ws_size;

  const dim3 tb(32, 8);
  // 1) transpose all weights to [out, in] (Bt layout), fp32 -> bf16
  transpose_to_bf16<float><<<dim3(32, 32, 8), tb, 0, stream>>>(
      expert_w, expertT, 1024, 1024, 1024, 1024, 1024, 1048576L, 1048576L);
  transpose_to_bf16<float><<<dim3(96, 32, 1), tb, 0, stream>>>(
      in_proj_w, inprojT, 1024, 3072, 3072, 3072, 1024, 0, 0);
  transpose_to_bf16<float><<<dim3(32, 32, 1), tb, 0, stream>>>(
      out_proj_w, outprojT, 1024, 1024, 1024, 1024, 1024, 0, 0);
  transpose_to_bf16<float><<<dim3(128, 32, 1), tb, 0, stream>>>(
      ff1_w, ff1T, 1024, 4096, 4096, 4096, 1024, 0, 0);
  transpose_to_bf16<float><<<dim3(16, 128, 1), tb, 0, stream>>>(
      ff2_w, ff2T, 4096, ADIM, 512, ADIM, 4096, 0, 0);

  // 2) h (bf16), fp32 gate -> top-2, grouping
  build_h_kernel<<<dim3(SEQ), 256, 0, stream>>>(x, timev, state, ttab, h);
  gate_topk_kernel<<<dim3(SEQ), 64, 0, stream>>>(x, timev, state, ttab, gate_w,
                                                 gate_b, tok_e, tok_w);
  group_kernel<<<dim3(1), 256, 0, stream>>>(tok_e, slot_token, token_slot, eblk);

  // 3) grouped MoE: gather-GEMM over assigned (token, expert) pairs + combine
  gemm_moe<<<dim3(8, NSLOT / 128), 256, 0, stream>>>(h, expertT, slot_token,
                                                     eblk, slotout);
  moe_combine_kernel<<<dim3(SEQ), 256, 0, stream>>>(slotout, token_slot, tok_w,
                                                    tok_e, expert_b, moe);

  // 4) qkv = moe @ in_proj + b
  gemm_bt<<<dim3(24, 32, 1), 256, 0, stream>>>(moe, 1024, 0, inprojT, 1024, 0,
                                               qkv, 3072, 0, 1024, in_proj_b, 0);

  // 5) attention, two heads per pass (scores arena = 64 MB)
  for (int hp = 0; hp < 2; ++hp) {
    const hb* qb = qkv + hp * 512;
    const hb* kb = qkv + 1024 + hp * 512;
    const hb* vb = qkv + 2048 + hp * 512;
    gemm_bt<<<dim3(32, 32, 2), 256, 0, stream>>>(
        qb, 3072, 256, kb, 3072, 256, scores, 4096, (long)SEQ * SEQ, HDIM,
        nullptr, 0);
    softmax_rows_kernel<<<dim3(2 * SEQ), 256, 0, stream>>>(scores, SEQ, 0.0625f);
    transpose_to_bf16<hb><<<dim3(8, 128, 2), tb, 0, stream>>>(
        vb, vt, SEQ, HDIM, HDIM, 3072, 4096, 256L, 1048576L);
    gemm_bt<<<dim3(2, 32, 2), 256, 0, stream>>>(
        scores, 4096, (long)SEQ * SEQ, vt, 4096, 1048576L, ao + hp * 512, 1024,
        256, SEQ, nullptr, 0);
  }

  // 6) out_proj, residual LN
  gemm_bt<<<dim3(8, 32, 1), 256, 0, stream>>>(ao, 1024, 0, outprojT, 1024, 0,
                                              ao2, 1024, 0, 1024, out_proj_b, 0);
  ln_kernel<<<dim3(SEQ), 256, 0, stream>>>(moe, 1024, ao2, 1024, nullptr, ln1_g,
                                           ln1_b, out1, nullptr, 1024, 1024);

  // 7) FFN
  gemm_bt<<<dim3(32, 32, 1), 256, 0, stream>>>(out1, 1024, 0, ff1T, 1024, 0,
                                               ffmid, 4096, 0, 1024, ff1_b, 1);
  gemm_bt<<<dim3(4, 32, 1), 256, 0, stream>>>(ffmid, 4096, 0, ff2T, 4096, 0,
                                              ff2out, 512, 0, 4096, nullptr, 0);

  // 8) final LN over 496 cols -> d_out (fp32)
  ln_kernel<<<dim3(SEQ), 256, 0, stream>>>(ff2out, 512, nullptr, 0, ff2_b,
                                           ln2_g, ln2_b, nullptr, out, ADIM,
                                           ADIM);
}

// Round 5
// 652.482 us; speedup vs baseline: 1.5556x; 1.2910x over previous
//
#include <hip/hip_runtime.h>
#include <hip/hip_bf16.h>

typedef __hip_bfloat16 hb;
typedef __bf16 bf16x8 __attribute__((ext_vector_type(8)));
typedef float f32x4 __attribute__((ext_vector_type(4)));

#define SEQ 4096
#define EMBED 1024
#define NHEAD 4
#define HDIM 256
#define FFD 4096
#define NEXP 8
#define ADIM 496
#define NSLOT 9216  // 8192 assignments + 8 experts x 127 max padding, 128-aligned

static __device__ __forceinline__ float b2f(hb x) { return __bfloat162float(x); }
static __device__ __forceinline__ hb f2b(float x) { return __float2bfloat16(x); }
static __device__ __forceinline__ hb cvt_hb(float x) { return __float2bfloat16(x); }
static __device__ __forceinline__ hb cvt_hb(hb x) { return x; }

#define GLOAD_LDS16(g, l)                                                      \
  __builtin_amdgcn_global_load_lds(                                            \
      (const __attribute__((address_space(1))) void*)(g),                      \
      (__attribute__((address_space(3))) void*)(l), 16, 0, 0)

// ---------------------------------------------------------------------------
// Generic batched GEMM: C[M,N] = A[M,K] @ Bt[N,K]^T (+bias[col]) (+relu)
// 128x128 tile, BK=32, 4 waves (2x2 of 64x64), mfma_f32_16x16x32_bf16.
// LDS k-group XOR swizzle: 8-way bank conflict -> 2-way (free, m136).
// ---------------------------------------------------------------------------
__global__ __launch_bounds__(256) void gemm_bt(
    const hb* __restrict__ A, long lda, long bA,
    const hb* __restrict__ B, long ldb, long bB,
    hb* __restrict__ C, long ldc, long bC,
    int K, const float* __restrict__ bias, int relu) {
  __shared__ __align__(16) hb sA[128 * 32];
  __shared__ __align__(16) hb sB[128 * 32];
  const int z = blockIdx.z;
  A += (long)z * bA;
  B += (long)z * bB;
  C += (long)z * bC;
  const int m0 = blockIdx.y * 128, n0 = blockIdx.x * 128;
  const int tid = threadIdx.x;
  const int wave = tid >> 6, lane = tid & 63;
  const int quad = lane >> 4, lm = lane & 15;
  const int wr = wave >> 1, wc = wave & 1;

  const int r0 = tid >> 2;
  const int cg = 8 * ((tid & 3) ^ ((tid >> 2) & 3));  // XOR-swizzled k-group
  const hb* Ag0 = A + (long)(m0 + r0) * lda + cg;
  const hb* Ag1 = A + (long)(m0 + r0 + 64) * lda + cg;
  const hb* Bg0 = B + (long)(n0 + r0) * ldb + cg;
  const hb* Bg1 = B + (long)(n0 + r0 + 64) * ldb + cg;
  hb* sA0 = sA + wave * 512;
  hb* sA1 = sA + 2048 + wave * 512;
  hb* sB0 = sB + wave * 512;
  hb* sB1 = sB + 2048 + wave * 512;

  f32x4 acc[4][4] = {};

  for (int kt = 0; kt < K; kt += 32) {
    GLOAD_LDS16(Ag0 + kt, sA0);
    GLOAD_LDS16(Ag1 + kt, sA1);
    GLOAD_LDS16(Bg0 + kt, sB0);
    GLOAD_LDS16(Bg1 + kt, sB1);
    __syncthreads();
    bf16x8 av[4], bv[4];
#pragma unroll
    for (int i = 0; i < 4; i++) {
      const int row = wr * 64 + i * 16 + lm;
      av[i] = *(const bf16x8*)&sA[row * 32 + (quad ^ (lm & 3)) * 8];
    }
#pragma unroll
    for (int i = 0; i < 4; i++) {
      const int row = wc * 64 + i * 16 + lm;
      bv[i] = *(const bf16x8*)&sB[row * 32 + (quad ^ (lm & 3)) * 8];
    }
#pragma unroll
    for (int i = 0; i < 4; i++)
#pragma unroll
      for (int j = 0; j < 4; j++)
        acc[i][j] =
            __builtin_amdgcn_mfma_f32_16x16x32_bf16(av[i], bv[j], acc[i][j], 0, 0, 0);
    __syncthreads();
  }

#pragma unroll
  for (int j = 0; j < 4; j++) {
    const int col = n0 + wc * 64 + j * 16 + lm;
    const float bval = bias ? bias[col] : 0.f;
#pragma unroll
    for (int i = 0; i < 4; i++) {
      const int row = m0 + wr * 64 + i * 16 + quad * 4;
#pragma unroll
      for (int rr = 0; rr < 4; rr++) {
        float v = acc[i][j][rr] + bval;
        if (relu) v = fmaxf(v, 0.f);
        C[(long)(row + rr) * ldc + col] = f2b(v);
      }
    }
  }
}

// ---------------------------------------------------------------------------
// Split-K GEMM: partial[z] = A[batch][:, split*Ksub:+Ksub] @ Bt^T (fp32 out).
// z = (batch << shift) | split. Partials compact [M, ldcp] per z.
// Fixes tall-skinny shapes (PV N=256, ff2 N=512): 4x more blocks.
// ---------------------------------------------------------------------------
__global__ __launch_bounds__(256) void gemm_bt_splitk(
    const hb* __restrict__ A, long lda, long bA,
    const hb* __restrict__ B, long ldb, long bB,
    float* __restrict__ Cp, int ldcp, long pstride, int Ksub, int shift) {
  const int z = blockIdx.z;
  const int batch = z >> shift, split = z - (batch << shift);
  A += (long)batch * bA + (long)split * Ksub;
  B += (long)batch * bB + (long)split * Ksub;
  Cp += (long)z * pstride;
  __shared__ __align__(16) hb sA[128 * 32];
  __shared__ __align__(16) hb sB[128 * 32];
  const int m0 = blockIdx.y * 128, n0 = blockIdx.x * 128;
  const int tid = threadIdx.x;
  const int wave = tid >> 6, lane = tid & 63;
  const int quad = lane >> 4, lm = lane & 15;
  const int wr = wave >> 1, wc = wave & 1;

  const int r0 = tid >> 2;
  const int cg = 8 * ((tid & 3) ^ ((tid >> 2) & 3));
  const hb* Ag0 = A + (long)(m0 + r0) * lda + cg;
  const hb* Ag1 = A + (long)(m0 + r0 + 64) * lda + cg;
  const hb* Bg0 = B + (long)(n0 + r0) * ldb + cg;
  const hb* Bg1 = B + (long)(n0 + r0 + 64) * ldb + cg;
  hb* sA0 = sA + wave * 512;
  hb* sA1 = sA + 2048 + wave * 512;
  hb* sB0 = sB + wave * 512;
  hb* sB1 = sB + 2048 + wave * 512;

  f32x4 acc[4][4] = {};

  for (int kt = 0; kt < Ksub; kt += 32) {
    GLOAD_LDS16(Ag0 + kt, sA0);
    GLOAD_LDS16(Ag1 + kt, sA1);
    GLOAD_LDS16(Bg0 + kt, sB0);
    GLOAD_LDS16(Bg1 + kt, sB1);
    __syncthreads();
    bf16x8 av[4], bv[4];
#pragma unroll
    for (int i = 0; i < 4; i++) {
      const int row = wr * 64 + i * 16 + lm;
      av[i] = *(const bf16x8*)&sA[row * 32 + (quad ^ (lm & 3)) * 8];
    }
#pragma unroll
    for (int i = 0; i < 4; i++) {
      const int row = wc * 64 + i * 16 + lm;
      bv[i] = *(const bf16x8*)&sB[row * 32 + (quad ^ (lm & 3)) * 8];
    }
#pragma unroll
    for (int i = 0; i < 4; i++)
#pragma unroll
      for (int j = 0; j < 4; j++)
        acc[i][j] =
            __builtin_amdgcn_mfma_f32_16x16x32_bf16(av[i], bv[j], acc[i][j], 0, 0, 0);
    __syncthreads();
  }

#pragma unroll
  for (int j = 0; j < 4; j++) {
    const int col = n0 + wc * 64 + j * 16 + lm;
#pragma unroll
    for (int i = 0; i < 4; i++) {
      const int row = m0 + wr * 64 + i * 16 + quad * 4;
#pragma unroll
      for (int rr = 0; rr < 4; rr++)
        Cp[(long)(row + rr) * ldcp + col] = acc[i][j][rr];
    }
  }
}

// C[batch][row, col] = f2b(sum_k part[(batch<<shift)+k]); N = 1<<Nshift cols.
__global__ __launch_bounds__(256) void reduce_splitk(
    const float* __restrict__ part, long pstride, int nsplit, int shift,
    hb* __restrict__ C, long ldc, long bC, int Nshift) {
  const long idx = (long)blockIdx.x * 256 + threadIdx.x;
  const int batch = blockIdx.y;
  float v = 0.f;
  for (int k = 0; k < nsplit; k++)
    v += part[(long)((batch << shift) + k) * pstride + idx];
  const long row = idx >> Nshift;
  const long col = idx & ((1 << Nshift) - 1);
  C[(long)batch * bC + row * ldc + col] = f2b(v);
}

// ---------------------------------------------------------------------------
// MoE gather-GEMM: slotout[slot, :] = h[slot_token[slot], :] @ expertT[e]^T
// ---------------------------------------------------------------------------
__global__ __launch_bounds__(256) void gemm_moe(
    const hb* __restrict__ h, const hb* __restrict__ expertT,
    const int* __restrict__ slot_token, const int* __restrict__ eblk,
    hb* __restrict__ slotout) {
  const int e = eblk[blockIdx.y];
  if (e < 0) return;
  __shared__ __align__(16) hb sA[128 * 32];
  __shared__ __align__(16) hb sB[128 * 32];
  const int m0 = blockIdx.y * 128, n0 = blockIdx.x * 128;
  const int tid = threadIdx.x;
  const int wave = tid >> 6, lane = tid & 63;
  const int quad = lane >> 4, lm = lane & 15;
  const int wr = wave >> 1, wc = wave & 1;

  const int r0 = tid >> 2;
  const int cg = 8 * ((tid & 3) ^ ((tid >> 2) & 3));
  const int t0 = slot_token[m0 + r0];
  const int t1 = slot_token[m0 + r0 + 64];
  const hb* B = expertT + ((long)e << 20);
  const hb* Ag0 = h + (long)t0 * EMBED + cg;
  const hb* Ag1 = h + (long)t1 * EMBED + cg;
  const hb* Bg0 = B + (long)(n0 + r0) * EMBED + cg;
  const hb* Bg1 = B + (long)(n0 + r0 + 64) * EMBED + cg;
  hb* sA0 = sA + wave * 512;
  hb* sA1 = sA + 2048 + wave * 512;
  hb* sB0 = sB + wave * 512;
  hb* sB1 = sB + 2048 + wave * 512;

  f32x4 acc[4][4] = {};

  for (int kt = 0; kt < EMBED; kt += 32) {
    GLOAD_LDS16(Ag0 + kt, sA0);
    GLOAD_LDS16(Ag1 + kt, sA1);
    GLOAD_LDS16(Bg0 + kt, sB0);
    GLOAD_LDS16(Bg1 + kt, sB1);
    __syncthreads();
    bf16x8 av[4], bv[4];
#pragma unroll
    for (int i = 0; i < 4; i++) {
      const int row = wr * 64 + i * 16 + lm;
      av[i] = *(const bf16x8*)&sA[row * 32 + (quad ^ (lm & 3)) * 8];
    }
#pragma unroll
    for (int i = 0; i < 4; i++) {
      const int row = wc * 64 + i * 16 + lm;
      bv[i] = *(const bf16x8*)&sB[row * 32 + (quad ^ (lm & 3)) * 8];
    }
#pragma unroll
    for (int i = 0; i < 4; i++)
#pragma unroll
      for (int j = 0; j < 4; j++)
        acc[i][j] =
            __builtin_amdgcn_mfma_f32_16x16x32_bf16(av[i], bv[j], acc[i][j], 0, 0, 0);
    __syncthreads();
  }

#pragma unroll
  for (int j = 0; j < 4; j++) {
    const int col = n0 + wc * 64 + j * 16 + lm;
#pragma unroll
    for (int i = 0; i < 4; i++) {
      const int row = m0 + wr * 64 + i * 16 + quad * 4;
#pragma unroll
      for (int rr = 0; rr < 4; rr++)
        slotout[(long)(row + rr) * EMBED + col] = f2b(acc[i][j][rr]);
    }
  }
}

// ---------------------------------------------------------------------------
// Batched transpose to bf16: out[c][r] = cvt(in[r][c]); zero-pads [Cin,Cout).
// ---------------------------------------------------------------------------
template <typename Tin>
__global__ __launch_bounds__(256) void transpose_to_bf16(
    const Tin* __restrict__ in, hb* __restrict__ out, int R, int Cin, int Cout,
    int ldin, int ldout, long inBatch, long outBatch) {
  __shared__ hb tile[32][33];
  const int z = blockIdx.z;
  in += (long)z * inBatch;
  out += (long)z * outBatch;
  const int c0 = blockIdx.x * 32, r0 = blockIdx.y * 32;
  const int tx = threadIdx.x, ty = threadIdx.y;  // 32 x 8
#pragma unroll
  for (int i = 0; i < 32; i += 8) {
    const int r = r0 + ty + i, c = c0 + tx;
    hb v = f2b(0.f);
    if (r < R && c < Cin) v = cvt_hb(in[(long)r * ldin + c]);
    tile[ty + i][tx] = v;
  }
  __syncthreads();
#pragma unroll
  for (int i = 0; i < 32; i += 8) {
    const int c = c0 + ty + i, r = r0 + tx;
    if (c < Cout && r < R) out[(long)c * ldout + r] = tile[tx][ty + i];
  }
}

// ---------------------------------------------------------------------------
// h = concat(x, time_table[time], state)   fp32 inputs -> bf16 [SEQ, EMBED]
// ---------------------------------------------------------------------------
__global__ __launch_bounds__(256) void build_h_kernel(
    const float* __restrict__ x, const int* __restrict__ timev,
    const float* __restrict__ state, const float* __restrict__ ttab,
    hb* __restrict__ h) {
  const int s = blockIdx.x;
  for (int c = threadIdx.x; c < EMBED; c += 256) {
    float v;
    if (c < ADIM)
      v = x[(long)s * ADIM + c];
    else if (c < ADIM + 16)
      v = ttab[timev[s] * 16 + (c - ADIM)];
    else
      v = state[(long)s * 512 + (c - 512)];
    h[(long)s * EMBED + c] = f2b(v);
  }
}

// ---------------------------------------------------------------------------
// gate logits in fp32 straight from raw inputs (top-k is discontinuous; must
// match fp32 reference). Writes top-2 (expert, prob) per token.
// ---------------------------------------------------------------------------
__global__ __launch_bounds__(64) void gate_topk_kernel(
    const float* __restrict__ x, const int* __restrict__ timev,
    const float* __restrict__ state, const float* __restrict__ ttab,
    const float* __restrict__ gw, const float* __restrict__ gb,
    int* __restrict__ tok_e, float* __restrict__ tok_w) {
  const int s = blockIdx.x;
  const int l = threadIdx.x;
  const int t = timev[s];
  float acc[8] = {0, 0, 0, 0, 0, 0, 0, 0};
  for (int e = l; e < EMBED; e += 64) {
    float hv;
    if (e < ADIM)
      hv = x[(long)s * ADIM + e];
    else if (e < ADIM + 16)
      hv = ttab[t * 16 + (e - ADIM)];
    else
      hv = state[(long)s * 512 + (e - 512)];
    const float* g = gw + e * 8;
#pragma unroll
    for (int n = 0; n < 8; n++) acc[n] += hv * g[n];
  }
#pragma unroll
  for (int o = 32; o; o >>= 1)
#pragma unroll
    for (int n = 0; n < 8; n++) acc[n] += __shfl_down(acc[n], o);
  if (l == 0) {
    float lg[8], m = -1e30f;
    for (int n = 0; n < 8; n++) {
      lg[n] = acc[n] + gb[n];
      m = fmaxf(m, lg[n]);
    }
    float den = 0.f;
    for (int n = 0; n < 8; n++) {
      lg[n] = expf(lg[n] - m);
      den += lg[n];
    }
    for (int n = 0; n < 8; n++) lg[n] /= den;
    int i1 = 0;
    for (int n = 1; n < 8; n++)
      if (lg[n] > lg[i1]) i1 = n;
    int i2 = (i1 == 0) ? 1 : 0;
    for (int n = 0; n < 8; n++) {
      if (n == i1) continue;
      if (lg[n] > lg[i2]) i2 = n;
    }
    tok_e[2 * s] = i1;
    tok_w[2 * s] = lg[i1];
    tok_e[2 * s + 1] = i2;
    tok_w[2 * s + 1] = lg[i2];
  }
}

// ---------------------------------------------------------------------------
// Single-block grouping: histogram -> 128-aligned segments -> slot assignment.
// ---------------------------------------------------------------------------
__global__ __launch_bounds__(256) void group_kernel(
    const int* __restrict__ tok_e, int* __restrict__ slot_token,
    int* __restrict__ token_slot, int* __restrict__ eblk) {
  __shared__ int cnt[8], off[9], cur[8];
  const int tid = threadIdx.x;
  if (tid < 8) cnt[tid] = 0;
  for (int i = tid; i < NSLOT; i += 256) slot_token[i] = 0;  // padding -> tok 0
  __syncthreads();
  for (int i = tid; i < 2 * SEQ; i += 256) atomicAdd(&cnt[tok_e[i]], 1);
  __syncthreads();
  if (tid == 0) {
    int o = 0;
    for (int n = 0; n < 8; n++) {
      off[n] = o;
      cur[n] = o;
      o += (cnt[n] + 127) & ~127;
    }
    off[8] = o;
  }
  __syncthreads();
  if (tid < NSLOT / 128) {
    const int rb = tid * 128;
    int e = -1;
    for (int n = 0; n < 8; n++)
      if (rb >= off[n] && rb < off[n + 1]) e = n;
    eblk[tid] = e;
  }
  for (int i = tid; i < 2 * SEQ; i += 256) {
    const int e = tok_e[i];
    const int slot = atomicAdd(&cur[e], 1);
    slot_token[slot] = i >> 1;
    token_slot[i] = slot;
  }
}

// moe[s,:] = sum_k w_k * (slotout[slot_k,:] + expert_b[e_k,:])
__global__ __launch_bounds__(256) void moe_combine_kernel(
    const hb* __restrict__ slotout, const int* __restrict__ token_slot,
    const float* __restrict__ tok_w, const int* __restrict__ tok_e,
    const float* __restrict__ eb, hb* __restrict__ moe) {
  const int s = blockIdx.x, tid = threadIdx.x;
  const int s0 = token_slot[2 * s], s1 = token_slot[2 * s + 1];
  const float w0 = tok_w[2 * s], w1 = tok_w[2 * s + 1];
  const int e0 = tok_e[2 * s], e1 = tok_e[2 * s + 1];
  const hb* r0 = slotout + (long)s0 * EMBED;
  const hb* r1 = slotout + (long)s1 * EMBED;
  const float* b0 = eb + e0 * EMBED;
  const float* b1 = eb + e1 * EMBED;
  for (int c = tid; c < EMBED; c += 256) {
    const float v = w0 * (b2f(r0[c]) + b0[c]) + w1 * (b2f(r1[c]) + b1[c]);
    moe[(long)s * EMBED + c] = f2b(v);
  }
}

// ---------------------------------------------------------------------------
// Single-pass register-resident softmax: 4096 cols, 16 elems/thread in VGPRs.
// One read + one write (vs 3 reads + 1 write for the streaming version).
// ---------------------------------------------------------------------------
__global__ __launch_bounds__(256) void softmax_fast(hb* __restrict__ S,
                                                    float scale) {
  const long row = blockIdx.x;
  const int tid = threadIdx.x, wv = tid >> 6, ln = tid & 63;
  hb* p = S + row * 4096 + tid * 16;
  __shared__ float red[4];
  bf16x8 a0 = *(const bf16x8*)p;
  bf16x8 a1 = *(const bf16x8*)(p + 8);
  float v[16];
#pragma unroll
  for (int i = 0; i < 8; i++) {
    v[i] = (float)a0[i];
    v[8 + i] = (float)a1[i];
  }
  float m = v[0];
#pragma unroll
  for (int i = 1; i < 16; i++) m = fmaxf(m, v[i]);
#pragma unroll
  for (int o = 32; o; o >>= 1) m = fmaxf(m, __shfl_down(m, o));
  if (ln == 0) red[wv] = m;
  __syncthreads();
  const float M = fmaxf(fmaxf(red[0], red[1]), fmaxf(red[2], red[3])) * scale;
  __syncthreads();
  float sum = 0.f;
#pragma unroll
  for (int i = 0; i < 16; i++) {
    v[i] = __expf(v[i] * scale - M);
    sum += v[i];
  }
#pragma unroll
  for (int o = 32; o; o >>= 1) sum += __shfl_down(sum, o);
  if (ln == 0) red[wv] = sum;
  __syncthreads();
  const float inv = 1.f / (red[0] + red[1] + red[2] + red[3]);
#pragma unroll
  for (int i = 0; i < 8; i++) {
    a0[i] = (__bf16)(v[i] * inv);
    a1[i] = (__bf16)(v[8 + i] * inv);
  }
  *(bf16x8*)p = a0;
  *(bf16x8*)(p + 8) = a1;
}

// ---------------------------------------------------------------------------
// LayerNorm over ncol: t = in + resid? + bias?; out = (t-mean)*rsqrt(var)*g+b
// ---------------------------------------------------------------------------
__global__ __launch_bounds__(256) void ln_kernel(
    const hb* __restrict__ in, long ldin, const hb* __restrict__ resid,
    long ldr, const float* __restrict__ bias, const float* __restrict__ g,
    const float* __restrict__ beta, hb* __restrict__ outb,
    float* __restrict__ outf, long ldout, int ncol) {
  const int s = blockIdx.x, tid = threadIdx.x, wv = tid >> 6, ln = tid & 63;
  __shared__ float buf[1024];
  __shared__ float red[4];
  float sum = 0.f, sq = 0.f;
  for (int c = tid; c < ncol; c += 256) {
    float v = b2f(in[(long)s * ldin + c]);
    if (resid) v += b2f(resid[(long)s * ldr + c]);
    if (bias) v += bias[c];
    buf[c] = v;
    sum += v;
    sq += v * v;
  }
#pragma unroll
  for (int o = 32; o; o >>= 1) sum += __shfl_down(sum, o);
  if (ln == 0) red[wv] = sum;
  __syncthreads();
  const float S = red[0] + red[1] + red[2] + red[3];
  __syncthreads();
#pragma unroll
  for (int o = 32; o; o >>= 1) sq += __shfl_down(sq, o);
  if (ln == 0) red[wv] = sq;
  __syncthreads();
  const float Q = red[0] + red[1] + red[2] + red[3];
  const float mean = S / ncol;
  const float var = Q / ncol - mean * mean;
  const float r = rsqrtf(var + 1e-5f);
  for (int c = tid; c < ncol; c += 256) {
    const float o = (buf[c] - mean) * r * g[c] + beta[c];
    if (outf)
      outf[(long)s * ldout + c] = o;
    else
      outb[(long)s * ldout + c] = f2b(o);
  }
}

// ---------------------------------------------------------------------------
extern "C" void kernel_launch(void* const* d_in, const int* in_sizes, int n_in,
                              void* d_out, int out_size, void* d_ws,
                              size_t ws_size, hipStream_t stream) {
  const float* x = (const float*)d_in[0];
  const int* timev = (const int*)d_in[1];
  const float* state = (const float*)d_in[2];
  const float* ttab = (const float*)d_in[3];
  const float* expert_w = (const float*)d_in[4];
  const float* expert_b = (const float*)d_in[5];
  const float* gate_w = (const float*)d_in[6];
  const float* gate_b = (const float*)d_in[7];
  const float* in_proj_w = (const float*)d_in[8];
  const float* in_proj_b = (const float*)d_in[9];
  const float* out_proj_w = (const float*)d_in[10];
  const float* out_proj_b = (const float*)d_in[11];
  const float* ln1_g = (const float*)d_in[12];
  const float* ln1_b = (const float*)d_in[13];
  const float* ff1_w = (const float*)d_in[14];
  const float* ff1_b = (const float*)d_in[15];
  const float* ff2_w = (const float*)d_in[16];
  const float* ff2_b = (const float*)d_in[17];
  const float* ln2_g = (const float*)d_in[18];
  const float* ln2_b = (const float*)d_in[19];
  float* out = (float*)d_out;

  char* w = (char*)d_ws;
  const long MB = 1048576;
  // arena with lifetime-based reuse (peak 164 MB):
  hb* expertT = (hb*)(w + 0 * MB);         // 16 MB, dead after gemm_moe
  float* part = (float*)(w + 16 * MB);     // 32 MB split-K partials (phase D/F)
  hb* slotout = (hb*)(w + 16 * MB);        // 18.9 MB, dead after combine
  hb* h = (hb*)(w + 35 * MB);              //  8 MB, dead after gemm_moe
  hb* inprojT = (hb*)(w + 43 * MB);        //  6 MB, dead after qkv GEMM
  hb* outprojT = (hb*)(w + 49 * MB);       //  2 MB
  hb* ff1T = (hb*)(w + 51 * MB);           //  8 MB
  hb* ff2T = (hb*)(w + 59 * MB);           //  4 MB
  int* tok_e = (int*)(w + 63 * MB);        // 32 KB
  float* tok_w = (float*)(w + 63 * MB + 32768);
  int* slot_token = (int*)(w + 63 * MB + 65536);   // 36 KB
  int* token_slot = (int*)(w + 63 * MB + 102400);  // 32 KB
  int* eblk = (int*)(w + 63 * MB + 135168);
  hb* moe = (hb*)(w + 64 * MB);            //  8 MB, live until ln1
  hb* qkv = (hb*)(w + 72 * MB);            // 24 MB, live through attention
  hb* scores = (hb*)(w + 96 * MB);         // 64 MB, attention only
  hb* vt = (hb*)(w + 160 * MB);            //  4 MB
  hb* ao = (hb*)(w + 0 * MB);              //  8 MB (expertT region, dead)
  hb* ao2 = (hb*)(w + 8 * MB);             //  8 MB (expertT region, dead)
  hb* ffmid = (hb*)(w + 96 * MB);          // 32 MB (scores region, dead)
  hb* ff2out = (hb*)(w + 128 * MB);        //  4 MB (scores region)
  hb* out1 = (hb*)(w + 132 * MB);          //  8 MB (scores region)
  (void)in_sizes; (void)n_in; (void)out_size; (void)ws_size;

  const dim3 tb(32, 8);
  // 1) transpose all weights to [out, in] (Bt layout), fp32 -> bf16
  transpose_to_bf16<float><<<dim3(32, 32, 8), tb, 0, stream>>>(
      expert_w, expertT, 1024, 1024, 1024, 1024, 1024, 1048576L, 1048576L);
  transpose_to_bf16<float><<<dim3(96, 32, 1), tb, 0, stream>>>(
      in_proj_w, inprojT, 1024, 3072, 3072, 3072, 1024, 0, 0);
  transpose_to_bf16<float><<<dim3(32, 32, 1), tb, 0, stream>>>(
      out_proj_w, outprojT, 1024, 1024, 1024, 1024, 1024, 0, 0);
  transpose_to_bf16<float><<<dim3(128, 32, 1), tb, 0, stream>>>(
      ff1_w, ff1T, 1024, 4096, 4096, 4096, 1024, 0, 0);
  transpose_to_bf16<float><<<dim3(16, 128, 1), tb, 0, stream>>>(
      ff2_w, ff2T, 4096, ADIM, 512, ADIM, 4096, 0, 0);

  // 2) h (bf16), fp32 gate -> top-2, grouping
  build_h_kernel<<<dim3(SEQ), 256, 0, stream>>>(x, timev, state, ttab, h);
  gate_topk_kernel<<<dim3(SEQ), 64, 0, stream>>>(x, timev, state, ttab, gate_w,
                                                 gate_b, tok_e, tok_w);
  group_kernel<<<dim3(1), 256, 0, stream>>>(tok_e, slot_token, token_slot, eblk);

  // 3) grouped MoE: gather-GEMM + combine
  gemm_moe<<<dim3(8, NSLOT / 128), 256, 0, stream>>>(h, expertT, slot_token,
                                                     eblk, slotout);
  moe_combine_kernel<<<dim3(SEQ), 256, 0, stream>>>(slotout, token_slot, tok_w,
                                                    tok_e, expert_b, moe);

  // 4) qkv = moe @ in_proj + b
  gemm_bt<<<dim3(24, 32, 1), 256, 0, stream>>>(moe, 1024, 0, inprojT, 1024, 0,
                                               qkv, 3072, 0, 1024, in_proj_b, 0);

  // 5) attention, two heads per pass; PV via split-K=4
  for (int hp = 0; hp < 2; ++hp) {
    const hb* qb = qkv + hp * 512;
    const hb* kb = qkv + 1024 + hp * 512;
    const hb* vb = qkv + 2048 + hp * 512;
    gemm_bt<<<dim3(32, 32, 2), 256, 0, stream>>>(
        qb, 3072, 256, kb, 3072, 256, scores, 4096, (long)SEQ * SEQ, HDIM,
        nullptr, 0);
    softmax_fast<<<dim3(2 * SEQ), 256, 0, stream>>>(scores, 0.0625f);
    transpose_to_bf16<hb><<<dim3(8, 128, 2), tb, 0, stream>>>(
        vb, vt, SEQ, HDIM, HDIM, 3072, 4096, 256L, 1048576L);
    // PV: [4096x4096] @ [256x4096]^T, 2 heads x 4 splits = 512 blocks
    gemm_bt_splitk<<<dim3(2, 32, 8), 256, 0, stream>>>(
        scores, 4096, (long)SEQ * SEQ, vt, 4096, 1048576L, part, 256,
        (long)SEQ * 256, 1024, 2);
    reduce_splitk<<<dim3(4096, 2), 256, 0, stream>>>(
        part, (long)SEQ * 256, 4, 2, ao + hp * 512, 1024, 256, 8);
  }

  // 6) out_proj, residual LN
  gemm_bt<<<dim3(8, 32, 1), 256, 0, stream>>>(ao, 1024, 0, outprojT, 1024, 0,
                                              ao2, 1024, 0, 1024, out_proj_b, 0);
  ln_kernel<<<dim3(SEQ), 256, 0, stream>>>(moe, 1024, ao2, 1024, nullptr, ln1_g,
                                           ln1_b, out1, nullptr, 1024, 1024);

  // 7) FFN; ff2 via split-K=4
  gemm_bt<<<dim3(32, 32, 1), 256, 0, stream>>>(out1, 1024, 0, ff1T, 1024, 0,
                                               ffmid, 4096, 0, 1024, ff1_b, 1);
  gemm_bt_splitk<<<dim3(4, 32, 4), 256, 0, stream>>>(
      ffmid, 4096, 0, ff2T, 4096, 0, part, 512, (long)SEQ * 512, 1024, 2);
  reduce_splitk<<<dim3(8192, 1), 256, 0, stream>>>(
      part, (long)SEQ * 512, 4, 2, ff2out, 512, 0, 9);

  // 8) final LN over 496 cols -> d_out (fp32)
  ln_kernel<<<dim3(SEQ), 256, 0, stream>>>(ff2out, 512, nullptr, 0, ff2_b,
                                           ln2_g, ln2_b, nullptr, out, ADIM,
                                           ADIM);
}

// Round 6
// 650.514 us; speedup vs baseline: 1.5603x; 1.0030x over previous
//
#include <hip/hip_runtime.h>
#include <hip/hip_bf16.h>

typedef __hip_bfloat16 hb;
typedef __bf16 bf16x8 __attribute__((ext_vector_type(8)));
typedef float f32x4 __attribute__((ext_vector_type(4)));

#define SEQ 4096
#define EMBED 1024
#define NHEAD 4
#define HDIM 256
#define FFD 4096
#define NEXP 8
#define ADIM 496
#define NSLOT 9216  // 8192 assignments + 8 experts x 127 max padding, 128-aligned

static __device__ __forceinline__ float b2f(hb x) { return __bfloat162float(x); }
static __device__ __forceinline__ hb f2b(float x) { return __float2bfloat16(x); }
static __device__ __forceinline__ hb cvt_hb(float x) { return __float2bfloat16(x); }
static __device__ __forceinline__ hb cvt_hb(hb x) { return x; }

#define GLOAD_LDS16(g, l)                                                      \
  __builtin_amdgcn_global_load_lds(                                            \
      (const __attribute__((address_space(1))) void*)(g),                      \
      (__attribute__((address_space(3))) void*)(l), 16, 0, 0)

// ---------------------------------------------------------------------------
// Shared GEMM K-loop body (macro to keep the 3 variants in sync).
// 128x128 tile, BK=32, 4 waves (2x2 of 64x64), mfma_f32_16x16x32_bf16.
// LDS k-group XOR swizzle: 8-way bank conflict -> 2-way (free, m136).
// ---------------------------------------------------------------------------
#define GEMM_KLOOP(KMAX)                                                       \
  for (int kt = 0; kt < (KMAX); kt += 32) {                                    \
    GLOAD_LDS16(Ag0 + kt, sA0);                                                \
    GLOAD_LDS16(Ag1 + kt, sA1);                                                \
    GLOAD_LDS16(Bg0 + kt, sB0);                                                \
    GLOAD_LDS16(Bg1 + kt, sB1);                                                \
    __syncthreads();                                                           \
    bf16x8 av[4], bv[4];                                                       \
    _Pragma("unroll") for (int i = 0; i < 4; i++) {                            \
      const int row = wr * 64 + i * 16 + lm;                                   \
      av[i] = *(const bf16x8*)&sA[row * 32 + (quad ^ (lm & 3)) * 8];           \
    }                                                                          \
    _Pragma("unroll") for (int i = 0; i < 4; i++) {                            \
      const int row = wc * 64 + i * 16 + lm;                                   \
      bv[i] = *(const bf16x8*)&sB[row * 32 + (quad ^ (lm & 3)) * 8];           \
    }                                                                          \
    _Pragma("unroll") for (int i = 0; i < 4; i++)                              \
        _Pragma("unroll") for (int j = 0; j < 4; j++) acc[i][j] =              \
        __builtin_amdgcn_mfma_f32_16x16x32_bf16(av[i], bv[j], acc[i][j], 0, 0, \
                                                0);                            \
    __syncthreads();                                                           \
  }

// ---------------------------------------------------------------------------
// Generic batched GEMM: C[M,N] = A[M,K] @ Bt[N,K]^T (+bias[col]) (+relu)
// Epilogue stages each wave's 64x64 tile through LDS (quad-XOR col-group
// swizzle) to emit full 128B-line bf16x8 stores: old per-scalar path was
// VALU-bound and caused partial-line write-allocate RMW fetches.
// ---------------------------------------------------------------------------
__global__ __launch_bounds__(256) void gemm_bt(
    const hb* __restrict__ A, long lda, long bA,
    const hb* __restrict__ B, long ldb, long bB,
    hb* __restrict__ C, long ldc, long bC,
    int K, const float* __restrict__ bias, int relu) {
  __shared__ __align__(16) hb smem[2 * 128 * 32];
  hb* sA = smem;
  hb* sB = smem + 4096;
  const int z = blockIdx.z;
  A += (long)z * bA;
  B += (long)z * bB;
  C += (long)z * bC;
  const int m0 = blockIdx.y * 128, n0 = blockIdx.x * 128;
  const int tid = threadIdx.x;
  const int wave = tid >> 6, lane = tid & 63;
  const int quad = lane >> 4, lm = lane & 15;
  const int wr = wave >> 1, wc = wave & 1;

  const int r0 = tid >> 2;
  const int cg = 8 * ((tid & 3) ^ ((tid >> 2) & 3));  // XOR-swizzled k-group
  const hb* Ag0 = A + (long)(m0 + r0) * lda + cg;
  const hb* Ag1 = A + (long)(m0 + r0 + 64) * lda + cg;
  const hb* Bg0 = B + (long)(n0 + r0) * ldb + cg;
  const hb* Bg1 = B + (long)(n0 + r0 + 64) * ldb + cg;
  hb* sA0 = sA + wave * 512;
  hb* sA1 = sA + 2048 + wave * 512;
  hb* sB0 = sB + wave * 512;
  hb* sB1 = sB + 2048 + wave * 512;

  f32x4 acc[4][4] = {};
  GEMM_KLOOP(K)

  // coalesced epilogue: per i-slice, wave-private 16x64 LDS stage
  hb* eb = smem + wave * 1024;
#pragma unroll
  for (int i = 0; i < 4; i++) {
#pragma unroll
    for (int j = 0; j < 4; j++) {
      const float bval = bias ? bias[n0 + wc * 64 + j * 16 + lm] : 0.f;
      const int c = ((j ^ quad) << 4) + lm;  // swizzled col
#pragma unroll
      for (int rr = 0; rr < 4; rr++) {
        float v = acc[i][j][rr] + bval;
        if (relu) v = fmaxf(v, 0.f);
        eb[(quad * 4 + rr) * 64 + c] = f2b(v);
      }
    }
#pragma unroll
    for (int p = 0; p < 2; p++) {
      const int r = p * 8 + (lane >> 3);
      const int cgc = lane & 7;
      const int gs = (cgc >> 1) ^ (r >> 2);
      const bf16x8 val = *(const bf16x8*)&eb[r * 64 + gs * 16 + (cgc & 1) * 8];
      const long grow = m0 + wr * 64 + i * 16 + r;
      *(bf16x8*)&C[grow * ldc + n0 + wc * 64 + cgc * 8] = val;
    }
  }
}

// ---------------------------------------------------------------------------
// Split-K GEMM: partial[z] = A[batch][:, split*Ksub:+Ksub] @ Bt^T (fp32 out).
// z = (batch << shift) | split. Coalesced f32x4 epilogue via LDS.
// ---------------------------------------------------------------------------
__global__ __launch_bounds__(256) void gemm_bt_splitk(
    const hb* __restrict__ A, long lda, long bA,
    const hb* __restrict__ B, long ldb, long bB,
    float* __restrict__ Cp, int ldcp, long pstride, int Ksub, int shift) {
  const int z = blockIdx.z;
  const int batch = z >> shift, split = z - (batch << shift);
  A += (long)batch * bA + (long)split * Ksub;
  B += (long)batch * bB + (long)split * Ksub;
  Cp += (long)z * pstride;
  __shared__ __align__(16) hb smem[2 * 128 * 32];
  hb* sA = smem;
  hb* sB = smem + 4096;
  const int m0 = blockIdx.y * 128, n0 = blockIdx.x * 128;
  const int tid = threadIdx.x;
  const int wave = tid >> 6, lane = tid & 63;
  const int quad = lane >> 4, lm = lane & 15;
  const int wr = wave >> 1, wc = wave & 1;

  const int r0 = tid >> 2;
  const int cg = 8 * ((tid & 3) ^ ((tid >> 2) & 3));
  const hb* Ag0 = A + (long)(m0 + r0) * lda + cg;
  const hb* Ag1 = A + (long)(m0 + r0 + 64) * lda + cg;
  const hb* Bg0 = B + (long)(n0 + r0) * ldb + cg;
  const hb* Bg1 = B + (long)(n0 + r0 + 64) * ldb + cg;
  hb* sA0 = sA + wave * 512;
  hb* sA1 = sA + 2048 + wave * 512;
  hb* sB0 = sB + wave * 512;
  hb* sB1 = sB + 2048 + wave * 512;

  f32x4 acc[4][4] = {};
  GEMM_KLOOP(Ksub)

  float* ef = (float*)smem + wave * 1024;  // 16x64 fp32 per wave
#pragma unroll
  for (int i = 0; i < 4; i++) {
#pragma unroll
    for (int j = 0; j < 4; j++) {
      const int c = ((j ^ quad) << 4) + lm;
#pragma unroll
      for (int rr = 0; rr < 4; rr++)
        ef[(quad * 4 + rr) * 64 + c] = acc[i][j][rr];
    }
#pragma unroll
    for (int p = 0; p < 4; p++) {
      const int r = p * 4 + (lane >> 4);
      const int cgc = lane & 15;
      const int gs = (cgc >> 2) ^ (r >> 2);
      const f32x4 val = *(const f32x4*)&ef[r * 64 + gs * 16 + (cgc & 3) * 4];
      const long grow = m0 + wr * 64 + i * 16 + r;
      *(f32x4*)&Cp[grow * ldcp + n0 + wc * 64 + cgc * 4] = val;
    }
  }
}

// C[batch][row, col] = f2b(sum_k part[(batch<<shift)+k]); N = 1<<Nshift cols.
__global__ __launch_bounds__(256) void reduce_splitk(
    const float* __restrict__ part, long pstride, int nsplit, int shift,
    hb* __restrict__ C, long ldc, long bC, int Nshift) {
  const long idx = (long)blockIdx.x * 256 + threadIdx.x;
  const int batch = blockIdx.y;
  float v = 0.f;
  for (int k = 0; k < nsplit; k++)
    v += part[(long)((batch << shift) + k) * pstride + idx];
  const long row = idx >> Nshift;
  const long col = idx & ((1 << Nshift) - 1);
  C[(long)batch * bC + row * ldc + col] = f2b(v);
}

// ---------------------------------------------------------------------------
// MoE gather-GEMM: slotout[slot, :] = h[slot_token[slot], :] @ expertT[e]^T
// ---------------------------------------------------------------------------
__global__ __launch_bounds__(256) void gemm_moe(
    const hb* __restrict__ h, const hb* __restrict__ expertT,
    const int* __restrict__ slot_token, const int* __restrict__ eblk,
    hb* __restrict__ slotout) {
  const int e = eblk[blockIdx.y];
  if (e < 0) return;
  __shared__ __align__(16) hb smem[2 * 128 * 32];
  hb* sA = smem;
  hb* sB = smem + 4096;
  const int m0 = blockIdx.y * 128, n0 = blockIdx.x * 128;
  const int tid = threadIdx.x;
  const int wave = tid >> 6, lane = tid & 63;
  const int quad = lane >> 4, lm = lane & 15;
  const int wr = wave >> 1, wc = wave & 1;

  const int r0 = tid >> 2;
  const int cg = 8 * ((tid & 3) ^ ((tid >> 2) & 3));
  const int t0 = slot_token[m0 + r0];
  const int t1 = slot_token[m0 + r0 + 64];
  const hb* B = expertT + ((long)e << 20);
  const hb* Ag0 = h + (long)t0 * EMBED + cg;
  const hb* Ag1 = h + (long)t1 * EMBED + cg;
  const hb* Bg0 = B + (long)(n0 + r0) * EMBED + cg;
  const hb* Bg1 = B + (long)(n0 + r0 + 64) * EMBED + cg;
  hb* sA0 = sA + wave * 512;
  hb* sA1 = sA + 2048 + wave * 512;
  hb* sB0 = sB + wave * 512;
  hb* sB1 = sB + 2048 + wave * 512;

  f32x4 acc[4][4] = {};
  GEMM_KLOOP(EMBED)

  hb* eb = smem + wave * 1024;
#pragma unroll
  for (int i = 0; i < 4; i++) {
#pragma unroll
    for (int j = 0; j < 4; j++) {
      const int c = ((j ^ quad) << 4) + lm;
#pragma unroll
      for (int rr = 0; rr < 4; rr++)
        eb[(quad * 4 + rr) * 64 + c] = f2b(acc[i][j][rr]);
    }
#pragma unroll
    for (int p = 0; p < 2; p++) {
      const int r = p * 8 + (lane >> 3);
      const int cgc = lane & 7;
      const int gs = (cgc >> 1) ^ (r >> 2);
      const bf16x8 val = *(const bf16x8*)&eb[r * 64 + gs * 16 + (cgc & 1) * 8];
      const long grow = m0 + wr * 64 + i * 16 + r;
      *(bf16x8*)&slotout[grow * EMBED + n0 + wc * 64 + cgc * 8] = val;
    }
  }
}

// ---------------------------------------------------------------------------
// Batched transpose to bf16: out[c][r] = cvt(in[r][c]); zero-pads [Cin,Cout).
// ---------------------------------------------------------------------------
template <typename Tin>
__global__ __launch_bounds__(256) void transpose_to_bf16(
    const Tin* __restrict__ in, hb* __restrict__ out, int R, int Cin, int Cout,
    int ldin, int ldout, long inBatch, long outBatch) {
  __shared__ hb tile[32][33];
  const int z = blockIdx.z;
  in += (long)z * inBatch;
  out += (long)z * outBatch;
  const int c0 = blockIdx.x * 32, r0 = blockIdx.y * 32;
  const int tx = threadIdx.x, ty = threadIdx.y;  // 32 x 8
#pragma unroll
  for (int i = 0; i < 32; i += 8) {
    const int r = r0 + ty + i, c = c0 + tx;
    hb v = f2b(0.f);
    if (r < R && c < Cin) v = cvt_hb(in[(long)r * ldin + c]);
    tile[ty + i][tx] = v;
  }
  __syncthreads();
#pragma unroll
  for (int i = 0; i < 32; i += 8) {
    const int c = c0 + ty + i, r = r0 + tx;
    if (c < Cout && r < R) out[(long)c * ldout + r] = tile[tx][ty + i];
  }
}

// ---------------------------------------------------------------------------
// h = concat(x, time_table[time], state)   fp32 inputs -> bf16 [SEQ, EMBED]
// ---------------------------------------------------------------------------
__global__ __launch_bounds__(256) void build_h_kernel(
    const float* __restrict__ x, const int* __restrict__ timev,
    const float* __restrict__ state, const float* __restrict__ ttab,
    hb* __restrict__ h) {
  const int s = blockIdx.x;
  for (int c = threadIdx.x; c < EMBED; c += 256) {
    float v;
    if (c < ADIM)
      v = x[(long)s * ADIM + c];
    else if (c < ADIM + 16)
      v = ttab[timev[s] * 16 + (c - ADIM)];
    else
      v = state[(long)s * 512 + (c - 512)];
    h[(long)s * EMBED + c] = f2b(v);
  }
}

// ---------------------------------------------------------------------------
// gate logits in fp32 straight from raw inputs (top-k is discontinuous; must
// match fp32 reference). Writes top-2 (expert, prob) per token.
// ---------------------------------------------------------------------------
__global__ __launch_bounds__(64) void gate_topk_kernel(
    const float* __restrict__ x, const int* __restrict__ timev,
    const float* __restrict__ state, const float* __restrict__ ttab,
    const float* __restrict__ gw, const float* __restrict__ gb,
    int* __restrict__ tok_e, float* __restrict__ tok_w) {
  const int s = blockIdx.x;
  const int l = threadIdx.x;
  const int t = timev[s];
  float acc[8] = {0, 0, 0, 0, 0, 0, 0, 0};
  for (int e = l; e < EMBED; e += 64) {
    float hv;
    if (e < ADIM)
      hv = x[(long)s * ADIM + e];
    else if (e < ADIM + 16)
      hv = ttab[t * 16 + (e - ADIM)];
    else
      hv = state[(long)s * 512 + (e - 512)];
    const float* g = gw + e * 8;
#pragma unroll
    for (int n = 0; n < 8; n++) acc[n] += hv * g[n];
  }
#pragma unroll
  for (int o = 32; o; o >>= 1)
#pragma unroll
    for (int n = 0; n < 8; n++) acc[n] += __shfl_down(acc[n], o);
  if (l == 0) {
    float lg[8], m = -1e30f;
    for (int n = 0; n < 8; n++) {
      lg[n] = acc[n] + gb[n];
      m = fmaxf(m, lg[n]);
    }
    float den = 0.f;
    for (int n = 0; n < 8; n++) {
      lg[n] = expf(lg[n] - m);
      den += lg[n];
    }
    for (int n = 0; n < 8; n++) lg[n] /= den;
    int i1 = 0;
    for (int n = 1; n < 8; n++)
      if (lg[n] > lg[i1]) i1 = n;
    int i2 = (i1 == 0) ? 1 : 0;
    for (int n = 0; n < 8; n++) {
      if (n == i1) continue;
      if (lg[n] > lg[i2]) i2 = n;
    }
    tok_e[2 * s] = i1;
    tok_w[2 * s] = lg[i1];
    tok_e[2 * s + 1] = i2;
    tok_w[2 * s + 1] = lg[i2];
  }
}

// ---------------------------------------------------------------------------
// Single-block grouping: histogram -> 128-aligned segments -> slot assignment.
// ---------------------------------------------------------------------------
__global__ __launch_bounds__(256) void group_kernel(
    const int* __restrict__ tok_e, int* __restrict__ slot_token,
    int* __restrict__ token_slot, int* __restrict__ eblk) {
  __shared__ int cnt[8], off[9], cur[8];
  const int tid = threadIdx.x;
  if (tid < 8) cnt[tid] = 0;
  for (int i = tid; i < NSLOT; i += 256) slot_token[i] = 0;  // padding -> tok 0
  __syncthreads();
  for (int i = tid; i < 2 * SEQ; i += 256) atomicAdd(&cnt[tok_e[i]], 1);
  __syncthreads();
  if (tid == 0) {
    int o = 0;
    for (int n = 0; n < 8; n++) {
      off[n] = o;
      cur[n] = o;
      o += (cnt[n] + 127) & ~127;
    }
    off[8] = o;
  }
  __syncthreads();
  if (tid < NSLOT / 128) {
    const int rb = tid * 128;
    int e = -1;
    for (int n = 0; n < 8; n++)
      if (rb >= off[n] && rb < off[n + 1]) e = n;
    eblk[tid] = e;
  }
  for (int i = tid; i < 2 * SEQ; i += 256) {
    const int e = tok_e[i];
    const int slot = atomicAdd(&cur[e], 1);
    slot_token[slot] = i >> 1;
    token_slot[i] = slot;
  }
}

// moe[s,:] = sum_k w_k * (slotout[slot_k,:] + expert_b[e_k,:])
__global__ __launch_bounds__(256) void moe_combine_kernel(
    const hb* __restrict__ slotout, const int* __restrict__ token_slot,
    const float* __restrict__ tok_w, const int* __restrict__ tok_e,
    const float* __restrict__ eb, hb* __restrict__ moe) {
  const int s = blockIdx.x, tid = threadIdx.x;
  const int s0 = token_slot[2 * s], s1 = token_slot[2 * s + 1];
  const float w0 = tok_w[2 * s], w1 = tok_w[2 * s + 1];
  const int e0 = tok_e[2 * s], e1 = tok_e[2 * s + 1];
  const hb* r0 = slotout + (long)s0 * EMBED;
  const hb* r1 = slotout + (long)s1 * EMBED;
  const float* b0 = eb + e0 * EMBED;
  const float* b1 = eb + e1 * EMBED;
  for (int c = tid; c < EMBED; c += 256) {
    const float v = w0 * (b2f(r0[c]) + b0[c]) + w1 * (b2f(r1[c]) + b1[c]);
    moe[(long)s * EMBED + c] = f2b(v);
  }
}

// ---------------------------------------------------------------------------
// Single-pass register-resident softmax: 4096 cols, 16 elems/thread in VGPRs.
// ---------------------------------------------------------------------------
__global__ __launch_bounds__(256) void softmax_fast(hb* __restrict__ S,
                                                    float scale) {
  const long row = blockIdx.x;
  const int tid = threadIdx.x, wv = tid >> 6, ln = tid & 63;
  hb* p = S + row * 4096 + tid * 16;
  __shared__ float red[4];
  bf16x8 a0 = *(const bf16x8*)p;
  bf16x8 a1 = *(const bf16x8*)(p + 8);
  float v[16];
#pragma unroll
  for (int i = 0; i < 8; i++) {
    v[i] = (float)a0[i];
    v[8 + i] = (float)a1[i];
  }
  float m = v[0];
#pragma unroll
  for (int i = 1; i < 16; i++) m = fmaxf(m, v[i]);
#pragma unroll
  for (int o = 32; o; o >>= 1) m = fmaxf(m, __shfl_down(m, o));
  if (ln == 0) red[wv] = m;
  __syncthreads();
  const float M = fmaxf(fmaxf(red[0], red[1]), fmaxf(red[2], red[3])) * scale;
  __syncthreads();
  float sum = 0.f;
#pragma unroll
  for (int i = 0; i < 16; i++) {
    v[i] = __expf(v[i] * scale - M);
    sum += v[i];
  }
#pragma unroll
  for (int o = 32; o; o >>= 1) sum += __shfl_down(sum, o);
  if (ln == 0) red[wv] = sum;
  __syncthreads();
  const float inv = 1.f / (red[0] + red[1] + red[2] + red[3]);
#pragma unroll
  for (int i = 0; i < 8; i++) {
    a0[i] = (__bf16)(v[i] * inv);
    a1[i] = (__bf16)(v[8 + i] * inv);
  }
  *(bf16x8*)p = a0;
  *(bf16x8*)(p + 8) = a1;
}

// ---------------------------------------------------------------------------
// LayerNorm over ncol: t = in + resid? + bias?; out = (t-mean)*rsqrt(var)*g+b
// ---------------------------------------------------------------------------
__global__ __launch_bounds__(256) void ln_kernel(
    const hb* __restrict__ in, long ldin, const hb* __restrict__ resid,
    long ldr, const float* __restrict__ bias, const float* __restrict__ g,
    const float* __restrict__ beta, hb* __restrict__ outb,
    float* __restrict__ outf, long ldout, int ncol) {
  const int s = blockIdx.x, tid = threadIdx.x, wv = tid >> 6, ln = tid & 63;
  __shared__ float buf[1024];
  __shared__ float red[4];
  float sum = 0.f, sq = 0.f;
  for (int c = tid; c < ncol; c += 256) {
    float v = b2f(in[(long)s * ldin + c]);
    if (resid) v += b2f(resid[(long)s * ldr + c]);
    if (bias) v += bias[c];
    buf[c] = v;
    sum += v;
    sq += v * v;
  }
#pragma unroll
  for (int o = 32; o; o >>= 1) sum += __shfl_down(sum, o);
  if (ln == 0) red[wv] = sum;
  __syncthreads();
  const float S = red[0] + red[1] + red[2] + red[3];
  __syncthreads();
#pragma unroll
  for (int o = 32; o; o >>= 1) sq += __shfl_down(sq, o);
  if (ln == 0) red[wv] = sq;
  __syncthreads();
  const float Q = red[0] + red[1] + red[2] + red[3];
  const float mean = S / ncol;
  const float var = Q / ncol - mean * mean;
  const float r = rsqrtf(var + 1e-5f);
  for (int c = tid; c < ncol; c += 256) {
    const float o = (buf[c] - mean) * r * g[c] + beta[c];
    if (outf)
      outf[(long)s * ldout + c] = o;
    else
      outb[(long)s * ldout + c] = f2b(o);
  }
}

// ---------------------------------------------------------------------------
extern "C" void kernel_launch(void* const* d_in, const int* in_sizes, int n_in,
                              void* d_out, int out_size, void* d_ws,
                              size_t ws_size, hipStream_t stream) {
  const float* x = (const float*)d_in[0];
  const int* timev = (const int*)d_in[1];
  const float* state = (const float*)d_in[2];
  const float* ttab = (const float*)d_in[3];
  const float* expert_w = (const float*)d_in[4];
  const float* expert_b = (const float*)d_in[5];
  const float* gate_w = (const float*)d_in[6];
  const float* gate_b = (const float*)d_in[7];
  const float* in_proj_w = (const float*)d_in[8];
  const float* in_proj_b = (const float*)d_in[9];
  const float* out_proj_w = (const float*)d_in[10];
  const float* out_proj_b = (const float*)d_in[11];
  const float* ln1_g = (const float*)d_in[12];
  const float* ln1_b = (const float*)d_in[13];
  const float* ff1_w = (const float*)d_in[14];
  const float* ff1_b = (const float*)d_in[15];
  const float* ff2_w = (const float*)d_in[16];
  const float* ff2_b = (const float*)d_in[17];
  const float* ln2_g = (const float*)d_in[18];
  const float* ln2_b = (const float*)d_in[19];
  float* out = (float*)d_out;

  char* w = (char*)d_ws;
  const long MB = 1048576;
  // arena with lifetime-based reuse (peak 164 MB):
  hb* expertT = (hb*)(w + 0 * MB);         // 16 MB, dead after gemm_moe
  float* part = (float*)(w + 16 * MB);     // 32 MB split-K partials (phase D/F)
  hb* slotout = (hb*)(w + 16 * MB);        // 18.9 MB, dead after combine
  hb* h = (hb*)(w + 35 * MB);              //  8 MB, dead after gemm_moe
  hb* inprojT = (hb*)(w + 43 * MB);        //  6 MB, dead after qkv GEMM
  hb* outprojT = (hb*)(w + 49 * MB);       //  2 MB
  hb* ff1T = (hb*)(w + 51 * MB);           //  8 MB
  hb* ff2T = (hb*)(w + 59 * MB);           //  4 MB
  int* tok_e = (int*)(w + 63 * MB);        // 32 KB
  float* tok_w = (float*)(w + 63 * MB + 32768);
  int* slot_token = (int*)(w + 63 * MB + 65536);   // 36 KB
  int* token_slot = (int*)(w + 63 * MB + 102400);  // 32 KB
  int* eblk = (int*)(w + 63 * MB + 135168);
  hb* moe = (hb*)(w + 64 * MB);            //  8 MB, live until ln1
  hb* qkv = (hb*)(w + 72 * MB);            // 24 MB, live through attention
  hb* scores = (hb*)(w + 96 * MB);         // 64 MB, attention only
  hb* vt = (hb*)(w + 160 * MB);            //  4 MB
  hb* ao = (hb*)(w + 0 * MB);              //  8 MB (expertT region, dead)
  hb* ao2 = (hb*)(w + 8 * MB);             //  8 MB (expertT region, dead)
  hb* ffmid = (hb*)(w + 96 * MB);          // 32 MB (scores region, dead)
  hb* ff2out = (hb*)(w + 128 * MB);        //  4 MB (scores region)
  hb* out1 = (hb*)(w + 132 * MB);          //  8 MB (scores region)
  (void)in_sizes; (void)n_in; (void)out_size; (void)ws_size;

  const dim3 tb(32, 8);
  // 1) transpose all weights to [out, in] (Bt layout), fp32 -> bf16
  transpose_to_bf16<float><<<dim3(32, 32, 8), tb, 0, stream>>>(
      expert_w, expertT, 1024, 1024, 1024, 1024, 1024, 1048576L, 1048576L);
  transpose_to_bf16<float><<<dim3(96, 32, 1), tb, 0, stream>>>(
      in_proj_w, inprojT, 1024, 3072, 3072, 3072, 1024, 0, 0);
  transpose_to_bf16<float><<<dim3(32, 32, 1), tb, 0, stream>>>(
      out_proj_w, outprojT, 1024, 1024, 1024, 1024, 1024, 0, 0);
  transpose_to_bf16<float><<<dim3(128, 32, 1), tb, 0, stream>>>(
      ff1_w, ff1T, 1024, 4096, 4096, 4096, 1024, 0, 0);
  transpose_to_bf16<float><<<dim3(16, 128, 1), tb, 0, stream>>>(
      ff2_w, ff2T, 4096, ADIM, 512, ADIM, 4096, 0, 0);

  // 2) h (bf16), fp32 gate -> top-2, grouping
  build_h_kernel<<<dim3(SEQ), 256, 0, stream>>>(x, timev, state, ttab, h);
  gate_topk_kernel<<<dim3(SEQ), 64, 0, stream>>>(x, timev, state, ttab, gate_w,
                                                 gate_b, tok_e, tok_w);
  group_kernel<<<dim3(1), 256, 0, stream>>>(tok_e, slot_token, token_slot, eblk);

  // 3) grouped MoE: gather-GEMM + combine
  gemm_moe<<<dim3(8, NSLOT / 128), 256, 0, stream>>>(h, expertT, slot_token,
                                                     eblk, slotout);
  moe_combine_kernel<<<dim3(SEQ), 256, 0, stream>>>(slotout, token_slot, tok_w,
                                                    tok_e, expert_b, moe);

  // 4) qkv = moe @ in_proj + b
  gemm_bt<<<dim3(24, 32, 1), 256, 0, stream>>>(moe, 1024, 0, inprojT, 1024, 0,
                                               qkv, 3072, 0, 1024, in_proj_b, 0);

  // 5) attention, two heads per pass; PV via split-K=4
  for (int hp = 0; hp < 2; ++hp) {
    const hb* qb = qkv + hp * 512;
    const hb* kb = qkv + 1024 + hp * 512;
    const hb* vb = qkv + 2048 + hp * 512;
    gemm_bt<<<dim3(32, 32, 2), 256, 0, stream>>>(
        qb, 3072, 256, kb, 3072, 256, scores, 4096, (long)SEQ * SEQ, HDIM,
        nullptr, 0);
    softmax_fast<<<dim3(2 * SEQ), 256, 0, stream>>>(scores, 0.0625f);
    transpose_to_bf16<hb><<<dim3(8, 128, 2), tb, 0, stream>>>(
        vb, vt, SEQ, HDIM, HDIM, 3072, 4096, 256L, 1048576L);
    // PV: [4096x4096] @ [256x4096]^T, 2 heads x 4 splits = 512 blocks
    gemm_bt_splitk<<<dim3(2, 32, 8), 256, 0, stream>>>(
        scores, 4096, (long)SEQ * SEQ, vt, 4096, 1048576L, part, 256,
        (long)SEQ * 256, 1024, 2);
    reduce_splitk<<<dim3(4096, 2), 256, 0, stream>>>(
        part, (long)SEQ * 256, 4, 2, ao + hp * 512, 1024, 256, 8);
  }

  // 6) out_proj, residual LN
  gemm_bt<<<dim3(8, 32, 1), 256, 0, stream>>>(ao, 1024, 0, outprojT, 1024, 0,
                                              ao2, 1024, 0, 1024, out_proj_b, 0);
  ln_kernel<<<dim3(SEQ), 256, 0, stream>>>(moe, 1024, ao2, 1024, nullptr, ln1_g,
                                           ln1_b, out1, nullptr, 1024, 1024);

  // 7) FFN; ff2 via split-K=4
  gemm_bt<<<dim3(32, 32, 1), 256, 0, stream>>>(out1, 1024, 0, ff1T, 1024, 0,
                                               ffmid, 4096, 0, 1024, ff1_b, 1);
  gemm_bt_splitk<<<dim3(4, 32, 4), 256, 0, stream>>>(
      ffmid, 4096, 0, ff2T, 4096, 0, part, 512, (long)SEQ * 512, 1024, 2);
  reduce_splitk<<<dim3(8192, 1), 256, 0, stream>>>(
      part, (long)SEQ * 512, 4, 2, ff2out, 512, 0, 9);

  // 8) final LN over 496 cols -> d_out (fp32)
  ln_kernel<<<dim3(SEQ), 256, 0, stream>>>(ff2out, 512, nullptr, 0, ff2_b,
                                           ln2_g, ln2_b, nullptr, out, ADIM,
                                           ADIM);
}

// Round 7
// 599.343 us; speedup vs baseline: 1.6935x; 1.0854x over previous
//
#include <hip/hip_runtime.h>
#include <hip/hip_bf16.h>

typedef __hip_bfloat16 hb;
typedef __bf16 bf16x8 __attribute__((ext_vector_type(8)));
typedef float f32x4 __attribute__((ext_vector_type(4)));

#define SEQ 4096
#define EMBED 1024
#define NHEAD 4
#define HDIM 256
#define FFD 4096
#define NEXP 8
#define ADIM 496
#define NSLOT 9216  // 8192 assignments + 8 experts x 127 max padding, 128-aligned

static __device__ __forceinline__ float b2f(hb x) { return __bfloat162float(x); }
static __device__ __forceinline__ hb f2b(float x) { return __float2bfloat16(x); }

#define GLOAD_LDS16(g, l)                                                      \
  __builtin_amdgcn_global_load_lds(                                            \
      (const __attribute__((address_space(1))) void*)(g),                      \
      (__attribute__((address_space(3))) void*)(l), 16, 0, 0)

// ---------------------------------------------------------------------------
// Shared GEMM K-loop, BK=64 (2 panels of 32): halves barrier count vs BK=32
// (each __syncthreads costs a full vmcnt(0) drain), doubles MFMA per barrier.
// LDS: 2 x 128x64 bf16 = 32 KB -> still <=5 blocks/CU. Panel-local XOR
// swizzle keeps fragment reads at the free 2-way conflict level.
// ---------------------------------------------------------------------------
#define GEMM_KLOOP64(KMAX)                                                     \
  for (int kt = 0; kt < (KMAX); kt += 64) {                                    \
    GLOAD_LDS16(Ag + kt, sA + wave * 512);                                     \
    GLOAD_LDS16(Ag + kt + 32, sA + 4096 + wave * 512);                         \
    GLOAD_LDS16(Ag + kt + 64 * lda_, sA + 2048 + wave * 512);                  \
    GLOAD_LDS16(Ag + kt + 64 * lda_ + 32, sA + 6144 + wave * 512);             \
    GLOAD_LDS16(Bg + kt, sB + wave * 512);                                     \
    GLOAD_LDS16(Bg + kt + 32, sB + 4096 + wave * 512);                         \
    GLOAD_LDS16(Bg + kt + 64 * ldb_, sB + 2048 + wave * 512);                  \
    GLOAD_LDS16(Bg + kt + 64 * ldb_ + 32, sB + 6144 + wave * 512);             \
    __syncthreads();                                                           \
    _Pragma("unroll") for (int ks = 0; ks < 2; ks++) {                         \
      bf16x8 av[4], bv[4];                                                     \
      _Pragma("unroll") for (int i = 0; i < 4; i++) {                          \
        const int row = wr * 64 + i * 16 + lm;                                 \
        av[i] = *(const bf16x8*)&sA[ks * 4096 + row * 32 + sw8];               \
      }                                                                        \
      _Pragma("unroll") for (int i = 0; i < 4; i++) {                          \
        const int row = wc * 64 + i * 16 + lm;                                 \
        bv[i] = *(const bf16x8*)&sB[ks * 4096 + row * 32 + sw8];               \
      }                                                                        \
      _Pragma("unroll") for (int i = 0; i < 4; i++)                            \
          _Pragma("unroll") for (int j = 0; j < 4; j++) acc[i][j] =            \
          __builtin_amdgcn_mfma_f32_16x16x32_bf16(av[i], bv[j], acc[i][j], 0,  \
                                                  0, 0);                       \
    }                                                                          \
    __syncthreads();                                                           \
  }

#define GEMM_PROLOGUE                                                          \
  const int m0 = blockIdx.y * 128, n0 = blockIdx.x * 128;                      \
  const int tid = threadIdx.x;                                                 \
  const int wave = tid >> 6, lane = tid & 63;                                  \
  const int quad = lane >> 4, lm = lane & 15;                                  \
  const int wr = wave >> 1, wc = wave & 1;                                     \
  const int r0 = tid >> 2;                                                     \
  const int cg = 8 * ((tid & 3) ^ ((tid >> 2) & 3));                           \
  const int sw8 = (quad ^ (lm & 3)) * 8;

// ---------------------------------------------------------------------------
// Generic batched GEMM: C[M,N] = A[M,K] @ Bt[N,K]^T (+bias[col]) (+relu)
// ---------------------------------------------------------------------------
__global__ __launch_bounds__(256) void gemm_bt(
    const hb* __restrict__ A, long lda, long bA,
    const hb* __restrict__ B, long ldb, long bB,
    hb* __restrict__ C, long ldc, long bC,
    int K, const float* __restrict__ bias, int relu) {
  __shared__ __align__(16) hb smem[2 * 128 * 64];
  hb* sA = smem;
  hb* sB = smem + 8192;
  const int z = blockIdx.z;
  A += (long)z * bA;
  B += (long)z * bB;
  C += (long)z * bC;
  GEMM_PROLOGUE
  const long lda_ = lda, ldb_ = ldb;
  const hb* Ag = A + (long)(m0 + r0) * lda + cg;
  const hb* Bg = B + (long)(n0 + r0) * ldb + cg;

  f32x4 acc[4][4] = {};
  GEMM_KLOOP64(K)

  // coalesced epilogue: per i-slice, wave-private 16x64 LDS stage
  hb* eb = smem + wave * 1024;
#pragma unroll
  for (int i = 0; i < 4; i++) {
#pragma unroll
    for (int j = 0; j < 4; j++) {
      const float bval = bias ? bias[n0 + wc * 64 + j * 16 + lm] : 0.f;
      const int c = ((j ^ quad) << 4) + lm;  // swizzled col
#pragma unroll
      for (int rr = 0; rr < 4; rr++) {
        float v = acc[i][j][rr] + bval;
        if (relu) v = fmaxf(v, 0.f);
        eb[(quad * 4 + rr) * 64 + c] = f2b(v);
      }
    }
#pragma unroll
    for (int p = 0; p < 2; p++) {
      const int r = p * 8 + (lane >> 3);
      const int cgc = lane & 7;
      const int gs = (cgc >> 1) ^ (r >> 2);
      const bf16x8 val = *(const bf16x8*)&eb[r * 64 + gs * 16 + (cgc & 1) * 8];
      const long grow = m0 + wr * 64 + i * 16 + r;
      *(bf16x8*)&C[grow * ldc + n0 + wc * 64 + cgc * 8] = val;
    }
  }
}

// ---------------------------------------------------------------------------
// Split-K GEMM: partial[z] = A[batch][:, split*Ksub:+Ksub] @ Bt^T (fp32 out).
// ---------------------------------------------------------------------------
__global__ __launch_bounds__(256) void gemm_bt_splitk(
    const hb* __restrict__ A, long lda, long bA,
    const hb* __restrict__ B, long ldb, long bB,
    float* __restrict__ Cp, int ldcp, long pstride, int Ksub, int shift) {
  const int z = blockIdx.z;
  const int batch = z >> shift, split = z - (batch << shift);
  A += (long)batch * bA + (long)split * Ksub;
  B += (long)batch * bB + (long)split * Ksub;
  Cp += (long)z * pstride;
  __shared__ __align__(16) hb smem[2 * 128 * 64];
  hb* sA = smem;
  hb* sB = smem + 8192;
  GEMM_PROLOGUE
  const long lda_ = lda, ldb_ = ldb;
  const hb* Ag = A + (long)(m0 + r0) * lda + cg;
  const hb* Bg = B + (long)(n0 + r0) * ldb + cg;

  f32x4 acc[4][4] = {};
  GEMM_KLOOP64(Ksub)

  float* ef = (float*)smem + wave * 1024;  // 16x64 fp32 per wave
#pragma unroll
  for (int i = 0; i < 4; i++) {
#pragma unroll
    for (int j = 0; j < 4; j++) {
      const int c = ((j ^ quad) << 4) + lm;
#pragma unroll
      for (int rr = 0; rr < 4; rr++)
        ef[(quad * 4 + rr) * 64 + c] = acc[i][j][rr];
    }
#pragma unroll
    for (int p = 0; p < 4; p++) {
      const int r = p * 4 + (lane >> 4);
      const int cgc = lane & 15;
      const int gs = (cgc >> 2) ^ (r >> 2);
      const f32x4 val = *(const f32x4*)&ef[r * 64 + gs * 16 + (cgc & 3) * 4];
      const long grow = m0 + wr * 64 + i * 16 + r;
      *(f32x4*)&Cp[grow * ldcp + n0 + wc * 64 + cgc * 4] = val;
    }
  }
}

// C[batch][row, col] = f2b(sum_k part[(batch<<shift)+k]); N = 1<<Nshift cols.
__global__ __launch_bounds__(256) void reduce_splitk(
    const float* __restrict__ part, long pstride, int nsplit, int shift,
    hb* __restrict__ C, long ldc, long bC, int Nshift) {
  const long idx = (long)blockIdx.x * 256 + threadIdx.x;
  const int batch = blockIdx.y;
  float v = 0.f;
  for (int k = 0; k < nsplit; k++)
    v += part[(long)((batch << shift) + k) * pstride + idx];
  const long row = idx >> Nshift;
  const long col = idx & ((1 << Nshift) - 1);
  C[(long)batch * bC + row * ldc + col] = f2b(v);
}

// ---------------------------------------------------------------------------
// MoE gather-GEMM: slotout[slot, :] = h[slot_token[slot], :] @ expertT[e]^T
// Gathered A rows: per-row pointers (rows 0-63 and 64-127 of the tile).
// ---------------------------------------------------------------------------
__global__ __launch_bounds__(256) void gemm_moe(
    const hb* __restrict__ h, const hb* __restrict__ expertT,
    const int* __restrict__ slot_token, const int* __restrict__ eblk,
    hb* __restrict__ slotout) {
  const int e = eblk[blockIdx.y];
  if (e < 0) return;
  __shared__ __align__(16) hb smem[2 * 128 * 64];
  hb* sA = smem;
  hb* sB = smem + 8192;
  GEMM_PROLOGUE
  const int t0 = slot_token[m0 + r0];
  const int t1 = slot_token[m0 + r0 + 64];
  const hb* B = expertT + ((long)e << 20);
  const hb* Ag0 = h + (long)t0 * EMBED + cg;
  const hb* Ag1 = h + (long)t1 * EMBED + cg;
  const hb* Bg = B + (long)(n0 + r0) * EMBED + cg;

  f32x4 acc[4][4] = {};
  for (int kt = 0; kt < EMBED; kt += 64) {
    GLOAD_LDS16(Ag0 + kt, sA + wave * 512);
    GLOAD_LDS16(Ag0 + kt + 32, sA + 4096 + wave * 512);
    GLOAD_LDS16(Ag1 + kt, sA + 2048 + wave * 512);
    GLOAD_LDS16(Ag1 + kt + 32, sA + 6144 + wave * 512);
    GLOAD_LDS16(Bg + kt, sB + wave * 512);
    GLOAD_LDS16(Bg + kt + 32, sB + 4096 + wave * 512);
    GLOAD_LDS16(Bg + kt + 64 * EMBED, sB + 2048 + wave * 512);
    GLOAD_LDS16(Bg + kt + 64 * EMBED + 32, sB + 6144 + wave * 512);
    __syncthreads();
#pragma unroll
    for (int ks = 0; ks < 2; ks++) {
      bf16x8 av[4], bv[4];
#pragma unroll
      for (int i = 0; i < 4; i++) {
        const int row = wr * 64 + i * 16 + lm;
        av[i] = *(const bf16x8*)&sA[ks * 4096 + row * 32 + sw8];
      }
#pragma unroll
      for (int i = 0; i < 4; i++) {
        const int row = wc * 64 + i * 16 + lm;
        bv[i] = *(const bf16x8*)&sB[ks * 4096 + row * 32 + sw8];
      }
#pragma unroll
      for (int i = 0; i < 4; i++)
#pragma unroll
        for (int j = 0; j < 4; j++)
          acc[i][j] = __builtin_amdgcn_mfma_f32_16x16x32_bf16(av[i], bv[j],
                                                              acc[i][j], 0, 0, 0);
    }
    __syncthreads();
  }

  hb* eb = smem + wave * 1024;
#pragma unroll
  for (int i = 0; i < 4; i++) {
#pragma unroll
    for (int j = 0; j < 4; j++) {
      const int c = ((j ^ quad) << 4) + lm;
#pragma unroll
      for (int rr = 0; rr < 4; rr++)
        eb[(quad * 4 + rr) * 64 + c] = f2b(acc[i][j][rr]);
    }
#pragma unroll
    for (int p = 0; p < 2; p++) {
      const int r = p * 8 + (lane >> 3);
      const int cgc = lane & 7;
      const int gs = (cgc >> 1) ^ (r >> 2);
      const bf16x8 val = *(const bf16x8*)&eb[r * 64 + gs * 16 + (cgc & 1) * 8];
      const long grow = m0 + wr * 64 + i * 16 + r;
      *(bf16x8*)&slotout[grow * EMBED + n0 + wc * 64 + cgc * 8] = val;
    }
  }
}

// ---------------------------------------------------------------------------
// ALL weight transposes in one dispatch (flat grid, job decode): kills 4
// inter-dispatch gaps. out[c][r] = bf16(in[r][c]); zero-pads [Cin,Cout).
// ---------------------------------------------------------------------------
__global__ __launch_bounds__(256) void transpose_all(
    const float* __restrict__ expert_w, const float* __restrict__ in_proj_w,
    const float* __restrict__ out_proj_w, const float* __restrict__ ff1_w,
    const float* __restrict__ ff2_w, hb* __restrict__ expertT,
    hb* __restrict__ inprojT, hb* __restrict__ outprojT, hb* __restrict__ ff1T,
    hb* __restrict__ ff2T) {
  const int b = blockIdx.x;
  const float* in;
  hb* outp;
  int R, Cin, Cout, ldin, ldout, bx, by;
  if (b < 8192) {  // expert_w: 8 x [1024,1024] -> [1024,1024]
    const int z = b >> 10, l = b & 1023;
    bx = l & 31; by = l >> 5;
    in = expert_w + (long)z * 1048576; outp = expertT + (long)z * 1048576;
    R = 1024; Cin = 1024; Cout = 1024; ldin = 1024; ldout = 1024;
  } else if (b < 11264) {  // in_proj: [1024,3072] -> [3072,1024]
    const int l = b - 8192;
    bx = l % 96; by = l / 96;
    in = in_proj_w; outp = inprojT;
    R = 1024; Cin = 3072; Cout = 3072; ldin = 3072; ldout = 1024;
  } else if (b < 12288) {  // out_proj: [1024,1024]
    const int l = b - 11264;
    bx = l & 31; by = l >> 5;
    in = out_proj_w; outp = outprojT;
    R = 1024; Cin = 1024; Cout = 1024; ldin = 1024; ldout = 1024;
  } else if (b < 16384) {  // ff1: [1024,4096] -> [4096,1024]
    const int l = b - 12288;
    bx = l & 127; by = l >> 7;
    in = ff1_w; outp = ff1T;
    R = 1024; Cin = 4096; Cout = 4096; ldin = 4096; ldout = 1024;
  } else {  // ff2: [4096,496] -> [512,4096] zero-padded
    const int l = b - 16384;
    bx = l & 15; by = l >> 4;
    in = ff2_w; outp = ff2T;
    R = 4096; Cin = 496; Cout = 512; ldin = 496; ldout = 4096;
  }
  __shared__ hb tile[32][33];
  const int c0 = bx * 32, r0 = by * 32;
  const int tx = threadIdx.x, ty = threadIdx.y;  // 32 x 8
#pragma unroll
  for (int i = 0; i < 32; i += 8) {
    const int r = r0 + ty + i, c = c0 + tx;
    hb v = f2b(0.f);
    if (r < R && c < Cin) v = f2b(in[(long)r * ldin + c]);
    tile[ty + i][tx] = v;
  }
  __syncthreads();
#pragma unroll
  for (int i = 0; i < 32; i += 8) {
    const int c = c0 + ty + i, r = r0 + tx;
    if (c < Cout && r < R) outp[(long)c * ldout + r] = tile[tx][ty + i];
  }
}

// bf16 transpose for V (per-head): out[c][r] = in[r][c]
__global__ __launch_bounds__(256) void transpose_v(
    const hb* __restrict__ in, hb* __restrict__ out) {
  __shared__ hb tile[32][33];
  const int z = blockIdx.z;
  in += (long)z * 256;
  out += (long)z * 1048576;
  const int c0 = blockIdx.x * 32, r0 = blockIdx.y * 32;
  const int tx = threadIdx.x, ty = threadIdx.y;
#pragma unroll
  for (int i = 0; i < 32; i += 8)
    tile[ty + i][tx] = in[(long)(r0 + ty + i) * 3072 + c0 + tx];
  __syncthreads();
#pragma unroll
  for (int i = 0; i < 32; i += 8)
    out[(long)(c0 + ty + i) * 4096 + r0 + tx] = tile[tx][ty + i];
}

// ---------------------------------------------------------------------------
// Fused: h = concat(x, t_emb, state) -> bf16, AND fp32 gate top-2.
// fp32 logit math (top-k is discontinuous; must match fp32 reference —
// reorder noise ~1e-7 is 3 orders below the decision margins that matter).
// ---------------------------------------------------------------------------
__global__ __launch_bounds__(256) void bh_gate_kernel(
    const float* __restrict__ x, const int* __restrict__ timev,
    const float* __restrict__ state, const float* __restrict__ ttab,
    const float* __restrict__ gw, const float* __restrict__ gb,
    hb* __restrict__ h, int* __restrict__ tok_e, float* __restrict__ tok_w) {
  const int s = blockIdx.x, tid = threadIdx.x;
  const int wv = tid >> 6, ln = tid & 63;
  const int t = timev[s];
  float acc[8] = {0, 0, 0, 0, 0, 0, 0, 0};
  for (int c = tid; c < EMBED; c += 256) {
    float v;
    if (c < ADIM)
      v = x[(long)s * ADIM + c];
    else if (c < ADIM + 16)
      v = ttab[t * 16 + (c - ADIM)];
    else
      v = state[(long)s * 512 + (c - 512)];
    h[(long)s * EMBED + c] = f2b(v);
    const float* g = gw + c * 8;
#pragma unroll
    for (int n = 0; n < 8; n++) acc[n] += v * g[n];
  }
#pragma unroll
  for (int o = 32; o; o >>= 1)
#pragma unroll
    for (int n = 0; n < 8; n++) acc[n] += __shfl_down(acc[n], o);
  __shared__ float red[4][8];
  if (ln == 0)
#pragma unroll
    for (int n = 0; n < 8; n++) red[wv][n] = acc[n];
  __syncthreads();
  if (tid == 0) {
    float lg[8], m = -1e30f;
    for (int n = 0; n < 8; n++) {
      lg[n] = red[0][n] + red[1][n] + red[2][n] + red[3][n] + gb[n];
      m = fmaxf(m, lg[n]);
    }
    float den = 0.f;
    for (int n = 0; n < 8; n++) {
      lg[n] = expf(lg[n] - m);
      den += lg[n];
    }
    for (int n = 0; n < 8; n++) lg[n] /= den;
    int i1 = 0;
    for (int n = 1; n < 8; n++)
      if (lg[n] > lg[i1]) i1 = n;
    int i2 = (i1 == 0) ? 1 : 0;
    for (int n = 0; n < 8; n++) {
      if (n == i1) continue;
      if (lg[n] > lg[i2]) i2 = n;
    }
    tok_e[2 * s] = i1;
    tok_w[2 * s] = lg[i1];
    tok_e[2 * s + 1] = i2;
    tok_w[2 * s + 1] = lg[i2];
  }
}

// ---------------------------------------------------------------------------
// Single-block grouping: histogram -> 128-aligned segments -> slot assignment.
// ---------------------------------------------------------------------------
__global__ __launch_bounds__(256) void group_kernel(
    const int* __restrict__ tok_e, int* __restrict__ slot_token,
    int* __restrict__ token_slot, int* __restrict__ eblk) {
  __shared__ int cnt[8], off[9], cur[8];
  const int tid = threadIdx.x;
  if (tid < 8) cnt[tid] = 0;
  for (int i = tid; i < NSLOT; i += 256) slot_token[i] = 0;  // padding -> tok 0
  __syncthreads();
  for (int i = tid; i < 2 * SEQ; i += 256) atomicAdd(&cnt[tok_e[i]], 1);
  __syncthreads();
  if (tid == 0) {
    int o = 0;
    for (int n = 0; n < 8; n++) {
      off[n] = o;
      cur[n] = o;
      o += (cnt[n] + 127) & ~127;
    }
    off[8] = o;
  }
  __syncthreads();
  if (tid < NSLOT / 128) {
    const int rb = tid * 128;
    int e = -1;
    for (int n = 0; n < 8; n++)
      if (rb >= off[n] && rb < off[n + 1]) e = n;
    eblk[tid] = e;
  }
  for (int i = tid; i < 2 * SEQ; i += 256) {
    const int e = tok_e[i];
    const int slot = atomicAdd(&cur[e], 1);
    slot_token[slot] = i >> 1;
    token_slot[i] = slot;
  }
}

// moe[s,:] = sum_k w_k * (slotout[slot_k,:] + expert_b[e_k,:])
__global__ __launch_bounds__(256) void moe_combine_kernel(
    const hb* __restrict__ slotout, const int* __restrict__ token_slot,
    const float* __restrict__ tok_w, const int* __restrict__ tok_e,
    const float* __restrict__ eb, hb* __restrict__ moe) {
  const int s = blockIdx.x, tid = threadIdx.x;
  const int s0 = token_slot[2 * s], s1 = token_slot[2 * s + 1];
  const float w0 = tok_w[2 * s], w1 = tok_w[2 * s + 1];
  const int e0 = tok_e[2 * s], e1 = tok_e[2 * s + 1];
  const hb* r0 = slotout + (long)s0 * EMBED;
  const hb* r1 = slotout + (long)s1 * EMBED;
  const float* b0 = eb + e0 * EMBED;
  const float* b1 = eb + e1 * EMBED;
  for (int c = tid; c < EMBED; c += 256) {
    const float v = w0 * (b2f(r0[c]) + b0[c]) + w1 * (b2f(r1[c]) + b1[c]);
    moe[(long)s * EMBED + c] = f2b(v);
  }
}

// ---------------------------------------------------------------------------
// Single-pass register-resident softmax: 4096 cols, 16 elems/thread in VGPRs.
// ---------------------------------------------------------------------------
__global__ __launch_bounds__(256) void softmax_fast(hb* __restrict__ S,
                                                    float scale) {
  const long row = blockIdx.x;
  const int tid = threadIdx.x, wv = tid >> 6, ln = tid & 63;
  hb* p = S + row * 4096 + tid * 16;
  __shared__ float red[4];
  bf16x8 a0 = *(const bf16x8*)p;
  bf16x8 a1 = *(const bf16x8*)(p + 8);
  float v[16];
#pragma unroll
  for (int i = 0; i < 8; i++) {
    v[i] = (float)a0[i];
    v[8 + i] = (float)a1[i];
  }
  float m = v[0];
#pragma unroll
  for (int i = 1; i < 16; i++) m = fmaxf(m, v[i]);
#pragma unroll
  for (int o = 32; o; o >>= 1) m = fmaxf(m, __shfl_down(m, o));
  if (ln == 0) red[wv] = m;
  __syncthreads();
  const float M = fmaxf(fmaxf(red[0], red[1]), fmaxf(red[2], red[3])) * scale;
  __syncthreads();
  float sum = 0.f;
#pragma unroll
  for (int i = 0; i < 16; i++) {
    v[i] = __expf(v[i] * scale - M);
    sum += v[i];
  }
#pragma unroll
  for (int o = 32; o; o >>= 1) sum += __shfl_down(sum, o);
  if (ln == 0) red[wv] = sum;
  __syncthreads();
  const float inv = 1.f / (red[0] + red[1] + red[2] + red[3]);
#pragma unroll
  for (int i = 0; i < 8; i++) {
    a0[i] = (__bf16)(v[i] * inv);
    a1[i] = (__bf16)(v[8 + i] * inv);
  }
  *(bf16x8*)p = a0;
  *(bf16x8*)(p + 8) = a1;
}

// ---------------------------------------------------------------------------
// LayerNorm over ncol: t = in + resid?; out = (t-mean)*rsqrt(var)*g+b (bf16)
// ---------------------------------------------------------------------------
__global__ __launch_bounds__(256) void ln_kernel(
    const hb* __restrict__ in, long ldin, const hb* __restrict__ resid,
    long ldr, const float* __restrict__ g, const float* __restrict__ beta,
    hb* __restrict__ outb, long ldout, int ncol) {
  const int s = blockIdx.x, tid = threadIdx.x, wv = tid >> 6, ln = tid & 63;
  __shared__ float buf[1024];
  __shared__ float red[4];
  float sum = 0.f, sq = 0.f;
  for (int c = tid; c < ncol; c += 256) {
    float v = b2f(in[(long)s * ldin + c]);
    if (resid) v += b2f(resid[(long)s * ldr + c]);
    buf[c] = v;
    sum += v;
    sq += v * v;
  }
#pragma unroll
  for (int o = 32; o; o >>= 1) sum += __shfl_down(sum, o);
  if (ln == 0) red[wv] = sum;
  __syncthreads();
  const float S = red[0] + red[1] + red[2] + red[3];
  __syncthreads();
#pragma unroll
  for (int o = 32; o; o >>= 1) sq += __shfl_down(sq, o);
  if (ln == 0) red[wv] = sq;
  __syncthreads();
  const float Q = red[0] + red[1] + red[2] + red[3];
  const float mean = S / ncol;
  const float var = Q / ncol - mean * mean;
  const float r = rsqrtf(var + 1e-5f);
  for (int c = tid; c < ncol; c += 256)
    outb[(long)s * ldout + c] = f2b((buf[c] - mean) * r * g[c] + beta[c]);
}

// ---------------------------------------------------------------------------
// Fused ff2 split-K reduce + bias + final LN over 496 cols -> fp32 d_out.
// part slabs z=0..3: [4096 x 512] fp32 each.
// ---------------------------------------------------------------------------
__global__ __launch_bounds__(256) void ln2_red_kernel(
    const float* __restrict__ part, long pstride,
    const float* __restrict__ bias, const float* __restrict__ g,
    const float* __restrict__ beta, float* __restrict__ out) {
  const int s = blockIdx.x, tid = threadIdx.x, wv = tid >> 6, ln = tid & 63;
  __shared__ float buf[512];
  __shared__ float red[4];
  float sum = 0.f, sq = 0.f;
  for (int c = tid; c < ADIM; c += 256) {
    const long idx = (long)s * 512 + c;
    float v = part[idx] + part[pstride + idx] + part[2 * pstride + idx] +
              part[3 * pstride + idx] + bias[c];
    buf[c] = v;
    sum += v;
    sq += v * v;
  }
#pragma unroll
  for (int o = 32; o; o >>= 1) sum += __shfl_down(sum, o);
  if (ln == 0) red[wv] = sum;
  __syncthreads();
  const float S = red[0] + red[1] + red[2] + red[3];
  __syncthreads();
#pragma unroll
  for (int o = 32; o; o >>= 1) sq += __shfl_down(sq, o);
  if (ln == 0) red[wv] = sq;
  __syncthreads();
  const float Q = red[0] + red[1] + red[2] + red[3];
  const float mean = S / ADIM;
  const float var = Q / ADIM - mean * mean;
  const float r = rsqrtf(var + 1e-5f);
  for (int c = tid; c < ADIM; c += 256)
    out[(long)s * ADIM + c] = (buf[c] - mean) * r * g[c] + beta[c];
}

// ---------------------------------------------------------------------------
extern "C" void kernel_launch(void* const* d_in, const int* in_sizes, int n_in,
                              void* d_out, int out_size, void* d_ws,
                              size_t ws_size, hipStream_t stream) {
  const float* x = (const float*)d_in[0];
  const int* timev = (const int*)d_in[1];
  const float* state = (const float*)d_in[2];
  const float* ttab = (const float*)d_in[3];
  const float* expert_w = (const float*)d_in[4];
  const float* expert_b = (const float*)d_in[5];
  const float* gate_w = (const float*)d_in[6];
  const float* gate_b = (const float*)d_in[7];
  const float* in_proj_w = (const float*)d_in[8];
  const float* in_proj_b = (const float*)d_in[9];
  const float* out_proj_w = (const float*)d_in[10];
  const float* out_proj_b = (const float*)d_in[11];
  const float* ln1_g = (const float*)d_in[12];
  const float* ln1_b = (const float*)d_in[13];
  const float* ff1_w = (const float*)d_in[14];
  const float* ff1_b = (const float*)d_in[15];
  const float* ff2_w = (const float*)d_in[16];
  const float* ff2_b = (const float*)d_in[17];
  const float* ln2_g = (const float*)d_in[18];
  const float* ln2_b = (const float*)d_in[19];
  float* out = (float*)d_out;

  char* w = (char*)d_ws;
  const long MB = 1048576;
  // arena with lifetime-based reuse (peak 164 MB):
  hb* expertT = (hb*)(w + 0 * MB);         // 16 MB, dead after gemm_moe
  float* part = (float*)(w + 16 * MB);     // 32 MB split-K partials (PV/ff2)
  hb* slotout = (hb*)(w + 16 * MB);        // 18.9 MB, dead after combine
  hb* h = (hb*)(w + 35 * MB);              //  8 MB, dead after gemm_moe
  hb* inprojT = (hb*)(w + 43 * MB);        //  6 MB, dead after qkv GEMM
  hb* outprojT = (hb*)(w + 49 * MB);       //  2 MB
  hb* ff1T = (hb*)(w + 51 * MB);           //  8 MB
  hb* ff2T = (hb*)(w + 59 * MB);           //  4 MB
  int* tok_e = (int*)(w + 63 * MB);        // 32 KB
  float* tok_w = (float*)(w + 63 * MB + 32768);
  int* slot_token = (int*)(w + 63 * MB + 65536);   // 36 KB
  int* token_slot = (int*)(w + 63 * MB + 102400);  // 32 KB
  int* eblk = (int*)(w + 63 * MB + 135168);
  hb* moe = (hb*)(w + 64 * MB);            //  8 MB, live until ln1
  hb* qkv = (hb*)(w + 72 * MB);            // 24 MB, live through attention
  hb* scores = (hb*)(w + 96 * MB);         // 64 MB, attention only
  hb* ao = (hb*)(w + 0 * MB);              //  8 MB (expertT region, dead)
  hb* vt = (hb*)(w + 8 * MB);              //  8 MB [4][256][4096]; dead before
  hb* ao2 = (hb*)(w + 8 * MB);             //  ao2 written after vt is dead
  hb* ffmid = (hb*)(w + 96 * MB);          // 32 MB (scores region, dead)
  hb* out1 = (hb*)(w + 132 * MB);          //  8 MB (scores region)
  (void)in_sizes; (void)n_in; (void)out_size; (void)ws_size;

  // 1) all weight transposes, one dispatch
  transpose_all<<<dim3(18432), dim3(32, 8), 0, stream>>>(
      expert_w, in_proj_w, out_proj_w, ff1_w, ff2_w, expertT, inprojT, outprojT,
      ff1T, ff2T);

  // 2) fused h + fp32 gate top-2, then grouping
  bh_gate_kernel<<<dim3(SEQ), 256, 0, stream>>>(x, timev, state, ttab, gate_w,
                                                gate_b, h, tok_e, tok_w);
  group_kernel<<<dim3(1), 256, 0, stream>>>(tok_e, slot_token, token_slot, eblk);

  // 3) grouped MoE: gather-GEMM + combine
  gemm_moe<<<dim3(8, NSLOT / 128), 256, 0, stream>>>(h, expertT, slot_token,
                                                     eblk, slotout);
  moe_combine_kernel<<<dim3(SEQ), 256, 0, stream>>>(slotout, token_slot, tok_w,
                                                    tok_e, expert_b, moe);

  // 4) qkv = moe @ in_proj + b; then V^T for all 4 heads (one dispatch)
  gemm_bt<<<dim3(24, 32, 1), 256, 0, stream>>>(moe, 1024, 0, inprojT, 1024, 0,
                                               qkv, 3072, 0, 1024, in_proj_b, 0);
  transpose_v<<<dim3(8, 128, 4), dim3(32, 8), 0, stream>>>(qkv + 2048, vt);

  // 5) attention, two heads per pass; PV via split-K=4
  for (int hp = 0; hp < 2; ++hp) {
    const hb* qb = qkv + hp * 512;
    const hb* kb = qkv + 1024 + hp * 512;
    gemm_bt<<<dim3(32, 32, 2), 256, 0, stream>>>(
        qb, 3072, 256, kb, 3072, 256, scores, 4096, (long)SEQ * SEQ, HDIM,
        nullptr, 0);
    softmax_fast<<<dim3(2 * SEQ), 256, 0, stream>>>(scores, 0.0625f);
    gemm_bt_splitk<<<dim3(2, 32, 8), 256, 0, stream>>>(
        scores, 4096, (long)SEQ * SEQ, vt + (long)hp * 2097152, 4096, 1048576L,
        part, 256, (long)SEQ * 256, 1024, 2);
    reduce_splitk<<<dim3(4096, 2), 256, 0, stream>>>(
        part, (long)SEQ * 256, 4, 2, ao + hp * 512, 1024, 256, 8);
  }

  // 6) out_proj, residual LN (ao2 overwrites dead vt region)
  gemm_bt<<<dim3(8, 32, 1), 256, 0, stream>>>(ao, 1024, 0, outprojT, 1024, 0,
                                              ao2, 1024, 0, 1024, out_proj_b, 0);
  ln_kernel<<<dim3(SEQ), 256, 0, stream>>>(moe, 1024, ao2, 1024, ln1_g, ln1_b,
                                           out1, 1024, 1024);

  // 7) FFN; ff2 via split-K=4, reduce fused into final LN
  gemm_bt<<<dim3(32, 32, 1), 256, 0, stream>>>(out1, 1024, 0, ff1T, 1024, 0,
                                               ffmid, 4096, 0, 1024, ff1_b, 1);
  gemm_bt_splitk<<<dim3(4, 32, 4), 256, 0, stream>>>(
      ffmid, 4096, 0, ff2T, 4096, 0, part, 512, (long)SEQ * 512, 1024, 2);
  ln2_red_kernel<<<dim3(SEQ), 256, 0, stream>>>(part, (long)SEQ * 512, ff2_b,
                                                ln2_g, ln2_b, out);
}

// Round 9
// 576.551 us; speedup vs baseline: 1.7605x; 1.0395x over previous
//
#include <hip/hip_runtime.h>
#include <hip/hip_bf16.h>

typedef __hip_bfloat16 hb;
typedef __bf16 bf16x8 __attribute__((ext_vector_type(8)));
typedef float f32x4 __attribute__((ext_vector_type(4)));

#define SEQ 4096
#define EMBED 1024
#define NHEAD 4
#define HDIM 256
#define FFD 4096
#define NEXP 8
#define ADIM 496
#define NSLOT 9216  // 8192 assignments + 8 experts x 127 max padding, 128-aligned

static __device__ __forceinline__ float b2f(hb x) { return __bfloat162float(x); }
static __device__ __forceinline__ hb f2b(float x) { return __float2bfloat16(x); }

#define GLOAD_LDS16(g, l)                                                      \
  __builtin_amdgcn_global_load_lds(                                            \
      (const __attribute__((address_space(1))) void*)(g),                      \
      (__attribute__((address_space(3))) void*)(l), 16, 0, 0)

// ---------------------------------------------------------------------------
// Shared GEMM K-loop, BK=64 (2 panels of 32): halves barrier count vs BK=32,
// doubles MFMA per barrier. LDS: 2 x 128x64 bf16 = 32 KB. Panel-local XOR
// swizzle keeps fragment reads at the free 2-way conflict level (m136).
// ---------------------------------------------------------------------------
#define GEMM_KLOOP64(KMAX)                                                     \
  for (int kt = 0; kt < (KMAX); kt += 64) {                                    \
    GLOAD_LDS16(Ag + kt, sA + wave * 512);                                     \
    GLOAD_LDS16(Ag + kt + 32, sA + 4096 + wave * 512);                         \
    GLOAD_LDS16(Ag + kt + 64 * lda_, sA + 2048 + wave * 512);                  \
    GLOAD_LDS16(Ag + kt + 64 * lda_ + 32, sA + 6144 + wave * 512);             \
    GLOAD_LDS16(Bg + kt, sB + wave * 512);                                     \
    GLOAD_LDS16(Bg + kt + 32, sB + 4096 + wave * 512);                         \
    GLOAD_LDS16(Bg + kt + 64 * ldb_, sB + 2048 + wave * 512);                  \
    GLOAD_LDS16(Bg + kt + 64 * ldb_ + 32, sB + 6144 + wave * 512);             \
    __syncthreads();                                                           \
    _Pragma("unroll") for (int ks = 0; ks < 2; ks++) {                         \
      bf16x8 av[4], bv[4];                                                     \
      _Pragma("unroll") for (int i = 0; i < 4; i++) {                          \
        const int row = wr * 64 + i * 16 + lm;                                 \
        av[i] = *(const bf16x8*)&sA[ks * 4096 + row * 32 + sw8];               \
      }                                                                        \
      _Pragma("unroll") for (int i = 0; i < 4; i++) {                          \
        const int row = wc * 64 + i * 16 + lm;                                 \
        bv[i] = *(const bf16x8*)&sB[ks * 4096 + row * 32 + sw8];               \
      }                                                                        \
      _Pragma("unroll") for (int i = 0; i < 4; i++)                            \
          _Pragma("unroll") for (int j = 0; j < 4; j++) acc[i][j] =            \
          __builtin_amdgcn_mfma_f32_16x16x32_bf16(av[i], bv[j], acc[i][j], 0,  \
                                                  0, 0);                       \
    }                                                                          \
    __syncthreads();                                                           \
  }

#define GEMM_PROLOGUE                                                          \
  const int m0 = blockIdx.y * 128, n0 = blockIdx.x * 128;                      \
  const int tid = threadIdx.x;                                                 \
  const int wave = tid >> 6, lane = tid & 63;                                  \
  const int quad = lane >> 4, lm = lane & 15;                                  \
  const int wr = wave >> 1, wc = wave & 1;                                     \
  const int r0 = tid >> 2;                                                     \
  const int cg = 8 * ((tid & 3) ^ ((tid >> 2) & 3));                           \
  const int sw8 = (quad ^ (lm & 3)) * 8;

// bf16 coalesced epilogue via wave-private LDS stage (full 128B lines)
#define EPILOGUE_B16(DST, LDC)                                                 \
  {                                                                            \
    hb* eb = smem + wave * 1024;                                               \
    _Pragma("unroll") for (int i = 0; i < 4; i++) {                            \
      _Pragma("unroll") for (int j = 0; j < 4; j++) {                          \
        const int c = ((j ^ quad) << 4) + lm;                                  \
        _Pragma("unroll") for (int rr = 0; rr < 4; rr++)                       \
            eb[(quad * 4 + rr) * 64 + c] = f2b(acc[i][j][rr]);                 \
      }                                                                        \
      _Pragma("unroll") for (int p = 0; p < 2; p++) {                          \
        const int r = p * 8 + (lane >> 3);                                     \
        const int cgc = lane & 7;                                              \
        const int gs = (cgc >> 1) ^ (r >> 2);                                  \
        const bf16x8 val =                                                     \
            *(const bf16x8*)&eb[r * 64 + gs * 16 + (cgc & 1) * 8];             \
        const long grow = m0 + wr * 64 + i * 16 + r;                           \
        *(bf16x8*)&DST[grow * (LDC) + n0 + wc * 64 + cgc * 8] = val;           \
      }                                                                        \
    }                                                                          \
  }

// ---------------------------------------------------------------------------
// Generic batched GEMM: C[M,N] = A[M,K] @ Bt[N,K]^T (+bias[col]) (+relu)
// ---------------------------------------------------------------------------
__global__ __launch_bounds__(256) void gemm_bt(
    const hb* __restrict__ A, long lda, long bA,
    const hb* __restrict__ B, long ldb, long bB,
    hb* __restrict__ C, long ldc, long bC,
    int K, const float* __restrict__ bias, int relu) {
  __shared__ __align__(16) hb smem[2 * 128 * 64];
  hb* sA = smem;
  hb* sB = smem + 8192;
  const int z = blockIdx.z;
  A += (long)z * bA;
  B += (long)z * bB;
  C += (long)z * bC;
  GEMM_PROLOGUE
  const long lda_ = lda, ldb_ = ldb;
  const hb* Ag = A + (long)(m0 + r0) * lda + cg;
  const hb* Bg = B + (long)(n0 + r0) * ldb + cg;

  f32x4 acc[4][4] = {};
  GEMM_KLOOP64(K)

  hb* eb = smem + wave * 1024;
#pragma unroll
  for (int i = 0; i < 4; i++) {
#pragma unroll
    for (int j = 0; j < 4; j++) {
      const float bval = bias ? bias[n0 + wc * 64 + j * 16 + lm] : 0.f;
      const int c = ((j ^ quad) << 4) + lm;  // swizzled col
#pragma unroll
      for (int rr = 0; rr < 4; rr++) {
        float v = acc[i][j][rr] + bval;
        if (relu) v = fmaxf(v, 0.f);
        eb[(quad * 4 + rr) * 64 + c] = f2b(v);
      }
    }
#pragma unroll
    for (int p = 0; p < 2; p++) {
      const int r = p * 8 + (lane >> 3);
      const int cgc = lane & 7;
      const int gs = (cgc >> 1) ^ (r >> 2);
      const bf16x8 val = *(const bf16x8*)&eb[r * 64 + gs * 16 + (cgc & 1) * 8];
      const long grow = m0 + wr * 64 + i * 16 + r;
      *(bf16x8*)&C[grow * ldc + n0 + wc * 64 + cgc * 8] = val;
    }
  }
}

// ---------------------------------------------------------------------------
// Split-K GEMM, fp32 partials: partial[z] = A[batch][:, s*Ksub:+Ksub] @ Bt^T
// ---------------------------------------------------------------------------
__global__ __launch_bounds__(256) void gemm_bt_splitk(
    const hb* __restrict__ A, long lda, long bA,
    const hb* __restrict__ B, long ldb, long bB,
    float* __restrict__ Cp, int ldcp, long pstride, int Ksub, int shift) {
  const int z = blockIdx.z;
  const int batch = z >> shift, split = z - (batch << shift);
  A += (long)batch * bA + (long)split * Ksub;
  B += (long)batch * bB + (long)split * Ksub;
  Cp += (long)z * pstride;
  __shared__ __align__(16) hb smem[2 * 128 * 64];
  hb* sA = smem;
  hb* sB = smem + 8192;
  GEMM_PROLOGUE
  const long lda_ = lda, ldb_ = ldb;
  const hb* Ag = A + (long)(m0 + r0) * lda + cg;
  const hb* Bg = B + (long)(n0 + r0) * ldb + cg;

  f32x4 acc[4][4] = {};
  GEMM_KLOOP64(Ksub)

  float* ef = (float*)smem + wave * 1024;  // 16x64 fp32 per wave
#pragma unroll
  for (int i = 0; i < 4; i++) {
#pragma unroll
    for (int j = 0; j < 4; j++) {
      const int c = ((j ^ quad) << 4) + lm;
#pragma unroll
      for (int rr = 0; rr < 4; rr++)
        ef[(quad * 4 + rr) * 64 + c] = acc[i][j][rr];
    }
#pragma unroll
    for (int p = 0; p < 4; p++) {
      const int r = p * 4 + (lane >> 4);
      const int cgc = lane & 15;
      const int gs = (cgc >> 2) ^ (r >> 2);
      const f32x4 val = *(const f32x4*)&ef[r * 64 + gs * 16 + (cgc & 3) * 4];
      const long grow = m0 + wr * 64 + i * 16 + r;
      *(f32x4*)&Cp[grow * ldcp + n0 + wc * 64 + cgc * 4] = val;
    }
  }
}

// ---------------------------------------------------------------------------
// Split-K GEMM, bf16 partials (each partial = full fp32 accumulation over
// Ksub, rounded once -> ~0.4% rel on ~5e-3 partials: negligible downstream).
// Used by big-path PV so all 8 (head,split) slabs fit in 16 MB of dead arena.
// ---------------------------------------------------------------------------
__global__ __launch_bounds__(256) void gemm_bt_splitk_b16(
    const hb* __restrict__ A, long lda, long bA,
    const hb* __restrict__ B, long ldb, long bB,
    hb* __restrict__ Cp, int ldcp, long pstride, int Ksub, int shift) {
  const int z = blockIdx.z;
  const int batch = z >> shift, split = z - (batch << shift);
  A += (long)batch * bA + (long)split * Ksub;
  B += (long)batch * bB + (long)split * Ksub;
  Cp += (long)z * pstride;
  __shared__ __align__(16) hb smem[2 * 128 * 64];
  hb* sA = smem;
  hb* sB = smem + 8192;
  GEMM_PROLOGUE
  const long lda_ = lda, ldb_ = ldb;
  const hb* Ag = A + (long)(m0 + r0) * lda + cg;
  const hb* Bg = B + (long)(n0 + r0) * ldb + cg;

  f32x4 acc[4][4] = {};
  GEMM_KLOOP64(Ksub)
  EPILOGUE_B16(Cp, ldcp)
}

// C[b][row,col] = f2b(sum_k part_fp32[(b<<shift)+k]); N = 1<<Nshift cols.
__global__ __launch_bounds__(256) void reduce_splitk(
    const float* __restrict__ part, long pstride, int nsplit, int shift,
    hb* __restrict__ C, long ldc, long bC, int Nshift) {
  const long idx = (long)blockIdx.x * 256 + threadIdx.x;
  const int batch = blockIdx.y;
  float v = 0.f;
  for (int k = 0; k < nsplit; k++)
    v += part[(long)((batch << shift) + k) * pstride + idx];
  const long row = idx >> Nshift;
  const long col = idx & ((1 << Nshift) - 1);
  C[(long)batch * bC + row * ldc + col] = f2b(v);
}

// bf16-partial variant
__global__ __launch_bounds__(256) void reduce_splitk_b16(
    const hb* __restrict__ part, long pstride, int nsplit, int shift,
    hb* __restrict__ C, long ldc, long bC, int Nshift) {
  const long idx = (long)blockIdx.x * 256 + threadIdx.x;
  const int batch = blockIdx.y;
  float v = 0.f;
  for (int k = 0; k < nsplit; k++)
    v += b2f(part[(long)((batch << shift) + k) * pstride + idx]);
  const long row = idx >> Nshift;
  const long col = idx & ((1 << Nshift) - 1);
  C[(long)batch * bC + row * ldc + col] = f2b(v);
}

// ---------------------------------------------------------------------------
// MoE gather-GEMM: slotout[slot, :] = h[slot_token[slot], :] @ expertT[e]^T
// ---------------------------------------------------------------------------
__global__ __launch_bounds__(256) void gemm_moe(
    const hb* __restrict__ h, const hb* __restrict__ expertT,
    const int* __restrict__ slot_token, const int* __restrict__ eblk,
    hb* __restrict__ slotout) {
  const int e = eblk[blockIdx.y];
  if (e < 0) return;
  __shared__ __align__(16) hb smem[2 * 128 * 64];
  hb* sA = smem;
  hb* sB = smem + 8192;
  GEMM_PROLOGUE
  const int t0 = slot_token[m0 + r0];
  const int t1 = slot_token[m0 + r0 + 64];
  const hb* B = expertT + ((long)e << 20);
  const hb* Ag0 = h + (long)t0 * EMBED + cg;
  const hb* Ag1 = h + (long)t1 * EMBED + cg;
  const hb* Bg = B + (long)(n0 + r0) * EMBED + cg;

  f32x4 acc[4][4] = {};
  for (int kt = 0; kt < EMBED; kt += 64) {
    GLOAD_LDS16(Ag0 + kt, sA + wave * 512);
    GLOAD_LDS16(Ag0 + kt + 32, sA + 4096 + wave * 512);
    GLOAD_LDS16(Ag1 + kt, sA + 2048 + wave * 512);
    GLOAD_LDS16(Ag1 + kt + 32, sA + 6144 + wave * 512);
    GLOAD_LDS16(Bg + kt, sB + wave * 512);
    GLOAD_LDS16(Bg + kt + 32, sB + 4096 + wave * 512);
    GLOAD_LDS16(Bg + kt + 64 * EMBED, sB + 2048 + wave * 512);
    GLOAD_LDS16(Bg + kt + 64 * EMBED + 32, sB + 6144 + wave * 512);
    __syncthreads();
#pragma unroll
    for (int ks = 0; ks < 2; ks++) {
      bf16x8 av[4], bv[4];
#pragma unroll
      for (int i = 0; i < 4; i++) {
        const int row = wr * 64 + i * 16 + lm;
        av[i] = *(const bf16x8*)&sA[ks * 4096 + row * 32 + sw8];
      }
#pragma unroll
      for (int i = 0; i < 4; i++) {
        const int row = wc * 64 + i * 16 + lm;
        bv[i] = *(const bf16x8*)&sB[ks * 4096 + row * 32 + sw8];
      }
#pragma unroll
      for (int i = 0; i < 4; i++)
#pragma unroll
        for (int j = 0; j < 4; j++)
          acc[i][j] = __builtin_amdgcn_mfma_f32_16x16x32_bf16(av[i], bv[j],
                                                              acc[i][j], 0, 0, 0);
    }
    __syncthreads();
  }
  EPILOGUE_B16(slotout, EMBED)
}

// ---------------------------------------------------------------------------
// ALL weight transposes in one dispatch (flat grid, job decode).
// ---------------------------------------------------------------------------
__global__ __launch_bounds__(256) void transpose_all(
    const float* __restrict__ expert_w, const float* __restrict__ in_proj_w,
    const float* __restrict__ out_proj_w, const float* __restrict__ ff1_w,
    const float* __restrict__ ff2_w, hb* __restrict__ expertT,
    hb* __restrict__ inprojT, hb* __restrict__ outprojT, hb* __restrict__ ff1T,
    hb* __restrict__ ff2T) {
  const int b = blockIdx.x;
  const float* in;
  hb* outp;
  int R, Cin, Cout, ldin, ldout, bx, by;
  if (b < 8192) {  // expert_w: 8 x [1024,1024] -> [1024,1024]
    const int z = b >> 10, l = b & 1023;
    bx = l & 31; by = l >> 5;
    in = expert_w + (long)z * 1048576; outp = expertT + (long)z * 1048576;
    R = 1024; Cin = 1024; Cout = 1024; ldin = 1024; ldout = 1024;
  } else if (b < 11264) {  // in_proj: [1024,3072] -> [3072,1024]
    const int l = b - 8192;
    bx = l % 96; by = l / 96;
    in = in_proj_w; outp = inprojT;
    R = 1024; Cin = 3072; Cout = 3072; ldin = 3072; ldout = 1024;
  } else if (b < 12288) {  // out_proj: [1024,1024]
    const int l = b - 11264;
    bx = l & 31; by = l >> 5;
    in = out_proj_w; outp = outprojT;
    R = 1024; Cin = 1024; Cout = 1024; ldin = 1024; ldout = 1024;
  } else if (b < 16384) {  // ff1: [1024,4096] -> [4096,1024]
    const int l = b - 12288;
    bx = l & 127; by = l >> 7;
    in = ff1_w; outp = ff1T;
    R = 1024; Cin = 4096; Cout = 4096; ldin = 4096; ldout = 1024;
  } else {  // ff2: [4096,496] -> [512,4096] zero-padded
    const int l = b - 16384;
    bx = l & 15; by = l >> 4;
    in = ff2_w; outp = ff2T;
    R = 4096; Cin = 496; Cout = 512; ldin = 496; ldout = 4096;
  }
  __shared__ hb tile[32][33];
  const int c0 = bx * 32, r0 = by * 32;
  const int tx = threadIdx.x, ty = threadIdx.y;  // 32 x 8
#pragma unroll
  for (int i = 0; i < 32; i += 8) {
    const int r = r0 + ty + i, c = c0 + tx;
    hb v = f2b(0.f);
    if (r < R && c < Cin) v = f2b(in[(long)r * ldin + c]);
    tile[ty + i][tx] = v;
  }
  __syncthreads();
#pragma unroll
  for (int i = 0; i < 32; i += 8) {
    const int c = c0 + ty + i, r = r0 + tx;
    if (c < Cout && r < R) outp[(long)c * ldout + r] = tile[tx][ty + i];
  }
}

// bf16 transpose for V (per-head): out[c][r] = in[r][c]
__global__ __launch_bounds__(256) void transpose_v(
    const hb* __restrict__ in, hb* __restrict__ out) {
  __shared__ hb tile[32][33];
  const int z = blockIdx.z;
  in += (long)z * 256;
  out += (long)z * 1048576;
  const int c0 = blockIdx.x * 32, r0 = blockIdx.y * 32;
  const int tx = threadIdx.x, ty = threadIdx.y;
#pragma unroll
  for (int i = 0; i < 32; i += 8)
    tile[ty + i][tx] = in[(long)(r0 + ty + i) * 3072 + c0 + tx];
  __syncthreads();
#pragma unroll
  for (int i = 0; i < 32; i += 8)
    out[(long)(c0 + ty + i) * 4096 + r0 + tx] = tile[tx][ty + i];
}

// ---------------------------------------------------------------------------
// Fused: h = concat(x, t_emb, state) -> bf16, AND fp32 gate top-2.
// ---------------------------------------------------------------------------
__global__ __launch_bounds__(256) void bh_gate_kernel(
    const float* __restrict__ x, const int* __restrict__ timev,
    const float* __restrict__ state, const float* __restrict__ ttab,
    const float* __restrict__ gw, const float* __restrict__ gb,
    hb* __restrict__ h, int* __restrict__ tok_e, float* __restrict__ tok_w) {
  const int s = blockIdx.x, tid = threadIdx.x;
  const int wv = tid >> 6, ln = tid & 63;
  const int t = timev[s];
  float acc[8] = {0, 0, 0, 0, 0, 0, 0, 0};
  for (int c = tid; c < EMBED; c += 256) {
    float v;
    if (c < ADIM)
      v = x[(long)s * ADIM + c];
    else if (c < ADIM + 16)
      v = ttab[t * 16 + (c - ADIM)];
    else
      v = state[(long)s * 512 + (c - 512)];
    h[(long)s * EMBED + c] = f2b(v);
    const float* g = gw + c * 8;
#pragma unroll
    for (int n = 0; n < 8; n++) acc[n] += v * g[n];
  }
#pragma unroll
  for (int o = 32; o; o >>= 1)
#pragma unroll
    for (int n = 0; n < 8; n++) acc[n] += __shfl_down(acc[n], o);
  __shared__ float red[4][8];
  if (ln == 0)
#pragma unroll
    for (int n = 0; n < 8; n++) red[wv][n] = acc[n];
  __syncthreads();
  if (tid == 0) {
    float lg[8], m = -1e30f;
    for (int n = 0; n < 8; n++) {
      lg[n] = red[0][n] + red[1][n] + red[2][n] + red[3][n] + gb[n];
      m = fmaxf(m, lg[n]);
    }
    float den = 0.f;
    for (int n = 0; n < 8; n++) {
      lg[n] = expf(lg[n] - m);
      den += lg[n];
    }
    for (int n = 0; n < 8; n++) lg[n] /= den;
    int i1 = 0;
    for (int n = 1; n < 8; n++)
      if (lg[n] > lg[i1]) i1 = n;
    int i2 = (i1 == 0) ? 1 : 0;
    for (int n = 0; n < 8; n++) {
      if (n == i1) continue;
      if (lg[n] > lg[i2]) i2 = n;
    }
    tok_e[2 * s] = i1;
    tok_w[2 * s] = lg[i1];
    tok_e[2 * s + 1] = i2;
    tok_w[2 * s + 1] = lg[i2];
  }
}

// ---------------------------------------------------------------------------
// Single-block grouping: histogram -> 128-aligned segments -> slot assignment.
// ---------------------------------------------------------------------------
__global__ __launch_bounds__(256) void group_kernel(
    const int* __restrict__ tok_e, int* __restrict__ slot_token,
    int* __restrict__ token_slot, int* __restrict__ eblk) {
  __shared__ int cnt[8], off[9], cur[8];
  const int tid = threadIdx.x;
  if (tid < 8) cnt[tid] = 0;
  for (int i = tid; i < NSLOT; i += 256) slot_token[i] = 0;  // padding -> tok 0
  __syncthreads();
  for (int i = tid; i < 2 * SEQ; i += 256) atomicAdd(&cnt[tok_e[i]], 1);
  __syncthreads();
  if (tid == 0) {
    int o = 0;
    for (int n = 0; n < 8; n++) {
      off[n] = o;
      cur[n] = o;
      o += (cnt[n] + 127) & ~127;
    }
    off[8] = o;
  }
  __syncthreads();
  if (tid < NSLOT / 128) {
    const int rb = tid * 128;
    int e = -1;
    for (int n = 0; n < 8; n++)
      if (rb >= off[n] && rb < off[n + 1]) e = n;
    eblk[tid] = e;
  }
  for (int i = tid; i < 2 * SEQ; i += 256) {
    const int e = tok_e[i];
    const int slot = atomicAdd(&cur[e], 1);
    slot_token[slot] = i >> 1;
    token_slot[i] = slot;
  }
}

// moe[s,:] = sum_k w_k * (slotout[slot_k,:] + expert_b[e_k,:])
__global__ __launch_bounds__(256) void moe_combine_kernel(
    const hb* __restrict__ slotout, const int* __restrict__ token_slot,
    const float* __restrict__ tok_w, const int* __restrict__ tok_e,
    const float* __restrict__ eb, hb* __restrict__ moe) {
  const int s = blockIdx.x, tid = threadIdx.x;
  const int s0 = token_slot[2 * s], s1 = token_slot[2 * s + 1];
  const float w0 = tok_w[2 * s], w1 = tok_w[2 * s + 1];
  const int e0 = tok_e[2 * s], e1 = tok_e[2 * s + 1];
  const hb* r0 = slotout + (long)s0 * EMBED;
  const hb* r1 = slotout + (long)s1 * EMBED;
  const float* b0 = eb + e0 * EMBED;
  const float* b1 = eb + e1 * EMBED;
  for (int c = tid; c < EMBED; c += 256) {
    const float v = w0 * (b2f(r0[c]) + b0[c]) + w1 * (b2f(r1[c]) + b1[c]);
    moe[(long)s * EMBED + c] = f2b(v);
  }
}

// ---------------------------------------------------------------------------
// Single-pass register-resident softmax: 4096 cols, 16 elems/thread in VGPRs.
// ---------------------------------------------------------------------------
__global__ __launch_bounds__(256) void softmax_fast(hb* __restrict__ S,
                                                    float scale) {
  const long row = blockIdx.x;
  const int tid = threadIdx.x, wv = tid >> 6, ln = tid & 63;
  hb* p = S + row * 4096 + tid * 16;
  __shared__ float red[4];
  bf16x8 a0 = *(const bf16x8*)p;
  bf16x8 a1 = *(const bf16x8*)(p + 8);
  float v[16];
#pragma unroll
  for (int i = 0; i < 8; i++) {
    v[i] = (float)a0[i];
    v[8 + i] = (float)a1[i];
  }
  float m = v[0];
#pragma unroll
  for (int i = 1; i < 16; i++) m = fmaxf(m, v[i]);
#pragma unroll
  for (int o = 32; o; o >>= 1) m = fmaxf(m, __shfl_down(m, o));
  if (ln == 0) red[wv] = m;
  __syncthreads();
  const float M = fmaxf(fmaxf(red[0], red[1]), fmaxf(red[2], red[3])) * scale;
  __syncthreads();
  float sum = 0.f;
#pragma unroll
  for (int i = 0; i < 16; i++) {
    v[i] = __expf(v[i] * scale - M);
    sum += v[i];
  }
#pragma unroll
  for (int o = 32; o; o >>= 1) sum += __shfl_down(sum, o);
  if (ln == 0) red[wv] = sum;
  __syncthreads();
  const float inv = 1.f / (red[0] + red[1] + red[2] + red[3]);
#pragma unroll
  for (int i = 0; i < 8; i++) {
    a0[i] = (__bf16)(v[i] * inv);
    a1[i] = (__bf16)(v[8 + i] * inv);
  }
  *(bf16x8*)p = a0;
  *(bf16x8*)(p + 8) = a1;
}

// ---------------------------------------------------------------------------
// LayerNorm over ncol: t = in + resid?; out = (t-mean)*rsqrt(var)*g+b (bf16)
// ---------------------------------------------------------------------------
__global__ __launch_bounds__(256) void ln_kernel(
    const hb* __restrict__ in, long ldin, const hb* __restrict__ resid,
    long ldr, const float* __restrict__ g, const float* __restrict__ beta,
    hb* __restrict__ outb, long ldout, int ncol) {
  const int s = blockIdx.x, tid = threadIdx.x, wv = tid >> 6, ln = tid & 63;
  __shared__ float buf[1024];
  __shared__ float red[4];
  float sum = 0.f, sq = 0.f;
  for (int c = tid; c < ncol; c += 256) {
    float v = b2f(in[(long)s * ldin + c]);
    if (resid) v += b2f(resid[(long)s * ldr + c]);
    buf[c] = v;
    sum += v;
    sq += v * v;
  }
#pragma unroll
  for (int o = 32; o; o >>= 1) sum += __shfl_down(sum, o);
  if (ln == 0) red[wv] = sum;
  __syncthreads();
  const float S = red[0] + red[1] + red[2] + red[3];
  __syncthreads();
#pragma unroll
  for (int o = 32; o; o >>= 1) sq += __shfl_down(sq, o);
  if (ln == 0) red[wv] = sq;
  __syncthreads();
  const float Q = red[0] + red[1] + red[2] + red[3];
  const float mean = S / ncol;
  const float var = Q / ncol - mean * mean;
  const float r = rsqrtf(var + 1e-5f);
  for (int c = tid; c < ncol; c += 256)
    outb[(long)s * ldout + c] = f2b((buf[c] - mean) * r * g[c] + beta[c]);
}

// ---------------------------------------------------------------------------
// Fused ff2 split-K reduce + bias + final LN over 496 cols -> fp32 d_out.
// ---------------------------------------------------------------------------
__global__ __launch_bounds__(256) void ln2_red_kernel(
    const float* __restrict__ part, long pstride,
    const float* __restrict__ bias, const float* __restrict__ g,
    const float* __restrict__ beta, float* __restrict__ out) {
  const int s = blockIdx.x, tid = threadIdx.x, wv = tid >> 6, ln = tid & 63;
  __shared__ float buf[512];
  __shared__ float red[4];
  float sum = 0.f, sq = 0.f;
  for (int c = tid; c < ADIM; c += 256) {
    const long idx = (long)s * 512 + c;
    float v = part[idx] + part[pstride + idx] + part[2 * pstride + idx] +
              part[3 * pstride + idx] + bias[c];
    buf[c] = v;
    sum += v;
    sq += v * v;
  }
#pragma unroll
  for (int o = 32; o; o >>= 1) sum += __shfl_down(sum, o);
  if (ln == 0) red[wv] = sum;
  __syncthreads();
  const float S = red[0] + red[1] + red[2] + red[3];
  __syncthreads();
#pragma unroll
  for (int o = 32; o; o >>= 1) sq += __shfl_down(sq, o);
  if (ln == 0) red[wv] = sq;
  __syncthreads();
  const float Q = red[0] + red[1] + red[2] + red[3];
  const float mean = S / ADIM;
  const float var = Q / ADIM - mean * mean;
  const float r = rsqrtf(var + 1e-5f);
  for (int c = tid; c < ADIM; c += 256)
    out[(long)s * ADIM + c] = (buf[c] - mean) * r * g[c] + beta[c];
}

// ---------------------------------------------------------------------------
extern "C" void kernel_launch(void* const* d_in, const int* in_sizes, int n_in,
                              void* d_out, int out_size, void* d_ws,
                              size_t ws_size, hipStream_t stream) {
  const float* x = (const float*)d_in[0];
  const int* timev = (const int*)d_in[1];
  const float* state = (const float*)d_in[2];
  const float* ttab = (const float*)d_in[3];
  const float* expert_w = (const float*)d_in[4];
  const float* expert_b = (const float*)d_in[5];
  const float* gate_w = (const float*)d_in[6];
  const float* gate_b = (const float*)d_in[7];
  const float* in_proj_w = (const float*)d_in[8];
  const float* in_proj_b = (const float*)d_in[9];
  const float* out_proj_w = (const float*)d_in[10];
  const float* out_proj_b = (const float*)d_in[11];
  const float* ln1_g = (const float*)d_in[12];
  const float* ln1_b = (const float*)d_in[13];
  const float* ff1_w = (const float*)d_in[14];
  const float* ff1_b = (const float*)d_in[15];
  const float* ff2_w = (const float*)d_in[16];
  const float* ff2_b = (const float*)d_in[17];
  const float* ln2_g = (const float*)d_in[18];
  const float* ln2_b = (const float*)d_in[19];
  float* out = (float*)d_out;

  char* w = (char*)d_ws;
  const long MB = 1048576;
  // big path (single-pass 4-head attention, 128 MB scores): peak 191 MB.
  // ws_size is constant per harness instance -> branch is graph-safe.
  const bool big = ws_size >= (size_t)(192 * MB);

  // ---- big-path lifetimes (audited):
  //  0-24  qkv        (written step4; dead after scores GEMM reads Q,K)
  //  0-16  pvpart     (bf16 PV partials; written AFTER scores GEMM -> safe)
  // 24-152 scores     (live scores GEMM .. PV)
  // 24-32  ao2 / 32-40 out1 / 40-72 ffmid / 72-104 part(ff2)  (post-attention)
  // 152-160 moe (live until ln1) | 160-168 vt | 168-182 weights | 182-190 ao
  hb* expertT = (hb*)(w + 0 * MB);          // 16 MB, dead after gemm_moe
  hb* slotout = (hb*)(w + 16 * MB);         // 18.9 MB, dead after combine
  hb* h = (hb*)(w + 35 * MB);               //  8 MB, dead after gemm_moe
  hb* inprojT = (hb*)(w + 43 * MB);         //  6 MB, dead after qkv GEMM
  hb* outprojT = (hb*)(w + (big ? 168 : 49) * MB);
  hb* ff1T = (hb*)(w + (big ? 170 : 51) * MB);
  hb* ff2T = (hb*)(w + (big ? 178 : 59) * MB);
  const long metaOff = (big ? 190 : 63) * MB;
  int* tok_e = (int*)(w + metaOff);
  float* tok_w = (float*)(w + metaOff + 32768);
  int* slot_token = (int*)(w + metaOff + 65536);
  int* token_slot = (int*)(w + metaOff + 102400);
  int* eblk = (int*)(w + metaOff + 135168);
  hb* moe = (hb*)(w + (big ? 152 : 64) * MB);   // live until ln1
  hb* qkv = (hb*)(w + (big ? 0 : 72) * MB);
  hb* scores = (hb*)(w + (big ? 24 : 96) * MB);
  hb* vt = (hb*)(w + (big ? 160 : 8) * MB);     // [4][256][4096]
  hb* ao = (hb*)(w + (big ? 182 : 0) * MB);
  hb* ao2 = (hb*)(w + (big ? 24 : 8) * MB);
  hb* out1 = (hb*)(w + (big ? 32 : 132) * MB);
  hb* ffmid = (hb*)(w + (big ? 40 : 96) * MB);
  float* part = (float*)(w + (big ? 72 : 16) * MB);  // fp32 split-K partials
  hb* pvpart = (hb*)(w + 0 * MB);  // big: 16 MB bf16 PV partials (qkv dead)
  (void)in_sizes; (void)n_in; (void)out_size;

  // 1) all weight transposes, one dispatch
  transpose_all<<<dim3(18432), dim3(32, 8), 0, stream>>>(
      expert_w, in_proj_w, out_proj_w, ff1_w, ff2_w, expertT, inprojT, outprojT,
      ff1T, ff2T);

  // 2) fused h + fp32 gate top-2, then grouping
  bh_gate_kernel<<<dim3(SEQ), 256, 0, stream>>>(x, timev, state, ttab, gate_w,
                                                gate_b, h, tok_e, tok_w);
  group_kernel<<<dim3(1), 256, 0, stream>>>(tok_e, slot_token, token_slot, eblk);

  // 3) grouped MoE: gather-GEMM + combine
  gemm_moe<<<dim3(8, NSLOT / 128), 256, 0, stream>>>(h, expertT, slot_token,
                                                     eblk, slotout);
  moe_combine_kernel<<<dim3(SEQ), 256, 0, stream>>>(slotout, token_slot, tok_w,
                                                    tok_e, expert_b, moe);

  // 4) qkv = moe @ in_proj + b; then V^T for all 4 heads
  gemm_bt<<<dim3(24, 32, 1), 256, 0, stream>>>(moe, 1024, 0, inprojT, 1024, 0,
                                               qkv, 3072, 0, 1024, in_proj_b, 0);
  transpose_v<<<dim3(8, 128, 4), dim3(32, 8), 0, stream>>>(qkv + 2048, vt);

  // 5) attention
  if (big) {
    // all 4 heads in one pass: scores / softmax / PV(split-K=2) / reduce.
    // PV partials are bf16 in the dead qkv region (NOT inside live scores).
    gemm_bt<<<dim3(32, 32, 4), 256, 0, stream>>>(
        qkv, 3072, 256, qkv + 1024, 3072, 256, scores, 4096, (long)SEQ * SEQ,
        HDIM, nullptr, 0);
    softmax_fast<<<dim3(4 * SEQ), 256, 0, stream>>>(scores, 0.0625f);
    gemm_bt_splitk_b16<<<dim3(2, 32, 8), 256, 0, stream>>>(
        scores, 4096, (long)SEQ * SEQ, vt, 4096, 1048576L, pvpart, 256,
        (long)SEQ * 256, 2048, 1);
    reduce_splitk_b16<<<dim3(4096, 4), 256, 0, stream>>>(
        pvpart, (long)SEQ * 256, 2, 1, ao, 1024, 256, 8);
  } else {
    for (int hp = 0; hp < 2; ++hp) {
      const hb* qb = qkv + hp * 512;
      const hb* kb = qkv + 1024 + hp * 512;
      gemm_bt<<<dim3(32, 32, 2), 256, 0, stream>>>(
          qb, 3072, 256, kb, 3072, 256, scores, 4096, (long)SEQ * SEQ, HDIM,
          nullptr, 0);
      softmax_fast<<<dim3(2 * SEQ), 256, 0, stream>>>(scores, 0.0625f);
      gemm_bt_splitk<<<dim3(2, 32, 8), 256, 0, stream>>>(
          scores, 4096, (long)SEQ * SEQ, vt + (long)hp * 2097152, 4096,
          1048576L, part, 256, (long)SEQ * 256, 1024, 2);
      reduce_splitk<<<dim3(4096, 2), 256, 0, stream>>>(
          part, (long)SEQ * 256, 4, 2, ao + hp * 512, 1024, 256, 8);
    }
  }

  // 6) out_proj, residual LN
  gemm_bt<<<dim3(8, 32, 1), 256, 0, stream>>>(ao, 1024, 0, outprojT, 1024, 0,
                                              ao2, 1024, 0, 1024, out_proj_b, 0);
  ln_kernel<<<dim3(SEQ), 256, 0, stream>>>(moe, 1024, ao2, 1024, ln1_g, ln1_b,
                                           out1, 1024, 1024);

  // 7) FFN; ff2 via split-K=4, reduce fused into final LN
  gemm_bt<<<dim3(32, 32, 1), 256, 0, stream>>>(out1, 1024, 0, ff1T, 1024, 0,
                                               ffmid, 4096, 0, 1024, ff1_b, 1);
  gemm_bt_splitk<<<dim3(4, 32, 4), 256, 0, stream>>>(
      ffmid, 4096, 0, ff2T, 4096, 0, part, 512, (long)SEQ * 512, 1024, 2);
  ln2_red_kernel<<<dim3(SEQ), 256, 0, stream>>>(part, (long)SEQ * 512, ff2_b,
                                                ln2_g, ln2_b, out);
}